// Round 6
// baseline (325.128 us; speedup 1.0000x reference)
//
#include <hip/hip_runtime.h>
#include <math.h>

// ---------------- problem constants ----------------
#define T_LEN   1024
#define HIDDEN  2048
#define QKVZ_N  6144   // 2*KEY_DIM + 2*VALUE_DIM
#define VAL_DIM 2048

typedef _Float16 half8 __attribute__((ext_vector_type(8)));
typedef _Float16 half4 __attribute__((ext_vector_type(4)));
typedef _Float16 half2t __attribute__((ext_vector_type(2)));
typedef float floatx4 __attribute__((ext_vector_type(4)));

__device__ __forceinline__ float sigmoidf_(float x) { return 1.f / (1.f + expf(-x)); }

// async global->LDS, 16B per lane; LDS dest = wave-uniform base + lane*16
__device__ __forceinline__ void gl_lds16(const _Float16* g, _Float16* l) {
    __builtin_amdgcn_global_load_lds(
        (const __attribute__((address_space(1))) void*)g,
        (__attribute__((address_space(3))) void*)l, 16, 0, 0);
}

// ---------------------------------------------------------------------------
// fp32 -> fp16 bulk convert of the two weight matrices (hidden is converted
// as a side-product of gemm_ba_gates, which reads it anyway).
// ---------------------------------------------------------------------------
__global__ __launch_bounds__(256) void cvt2(const float* __restrict__ s1, _Float16* __restrict__ d1, int n1,
                                            const float* __restrict__ s2, _Float16* __restrict__ d2, int n2) {
    int i = blockIdx.x * 256 + threadIdx.x;
    const float* s;
    _Float16* d;
    if (i < n1) { s = s1; d = d1; }
    else if (i < n1 + n2) { s = s2; d = d2; i -= n1; }
    else return;
    const float4 v = ((const float4*)s)[i];
    half4 h;
    h[0] = (_Float16)v.x; h[1] = (_Float16)v.y;
    h[2] = (_Float16)v.z; h[3] = (_Float16)v.w;
    *(half4*)&d[i * 4] = h;
}

// ---------------------------------------------------------------------------
// fp16 MFMA GEMM, A-direct + B-pipelined: C[M,N] = A[M,K]*W[N,K]^T.
// The R5 version was LDS-THROUGHPUT-bound (36 KB LDS traffic / 0.52 MFLOP
// per block-iter; MfmaUtil 21%).  Fix: the MFMA A-fragment is 16B/lane
// CONTIGUOUS in global memory (A[m][quad*8..+8]), so A is loaded directly
// global->VGPR in fragment layout (16-lane groups cover whole 64B lines, no
// inflation; A is 4MB, L2-resident across all n-panels).  This removes A's
// LDS writes AND reads: 36 -> 24 KB per block-iter (-33%).
// A-frags: named reg double-buffer aE/aO (loop unrolled x2, static indexing
// -- rule #20), prefetched 1 iter ahead.  B: 4-buffer gl_lds16, 2 ahead.
// Per iter: loadA(it+1) [2 ops] + stageB(it+2) [NT/2 ops], compute(it),
// s_waitcnt vmcnt(NT/2) -- completes B(it+1)+A(it+1), leaves B(it+2) in
// flight across the raw s_barrier (T4: never drain in main loop).
// Buffer-reuse distance 4 iters >= 2 barriers -> race-free.
// B swizzle (both sides, rule #21): chunk kq of row r at physical chunk
// P = (r*4 + (kq^(r&3))) ^ (r&4); staging inverts on the global address.
//   NT=4 (64x128): qkvz GEMM, grid 16x48 = 768 = 3/CU, LDS 32KB.
//   NT=2 (64x64):  out  GEMM, grid 16x32 = 512 = 2/CU, LDS 16KB.
// ---------------------------------------------------------------------------
template <int NT, typename OutT>
__global__ __launch_bounds__(256, 2) void gemm_h16(const _Float16* __restrict__ A,
                                                   const _Float16* __restrict__ W,
                                                   OutT* __restrict__ C,
                                                   int MB, int NB, int K) {
    const int BN = NT * 32;
    const int N = NB * BN;
    const int l = blockIdx.x;
    const int x = l & 7;
    const int tt = l >> 3;
    const int mb = tt % MB;
    const int nb = x + 8 * (tt / MB);
    const int m0 = mb * 64, n0 = nb * BN;

    const int t = threadIdx.x;
    const int wave = t >> 6;
    const int lane = t & 63;
    const int wr = (wave >> 1) * 32;        // wave row offset
    const int wc = (wave & 1) * (NT * 16);  // wave col offset
    const int l15 = lane & 15;
    const int quad = lane >> 4;

    __shared__ __align__(16) _Float16 Bh[4][BN * 32];

    // B staging: physical row R = base + (lane>>2), physical slot s = lane&3.
    const int Rl = lane >> 2, sl = lane & 3;

    // per-lane A fragment base pointers (row-major; 16B contiguous per lane)
    const _Float16* Arow0 = A + (size_t)(m0 + wr + l15) * K + quad * 8;
    const _Float16* Arow1 = Arow0 + (size_t)16 * K;

    floatx4 acc[2][NT];
#pragma unroll
    for (int i = 0; i < 2; ++i)
#pragma unroll
        for (int j = 0; j < NT; ++j) acc[i][j] = 0;

    auto stageB = [&](int buf, int k0) {
#pragma unroll
        for (int g = 0; g < NT / 2; ++g) {  // B: BN rows, NT/2 instr/wave
            const int R = wave * (NT * 8) + g * 16 + Rl;
            const int r = R ^ ((R >> 2) & 1);
            const int kq = sl ^ (r & 3);
            gl_lds16(W + (size_t)(n0 + r) * K + k0 + kq * 8,
                     &Bh[buf][(wave * (NT / 2) + g) * 512]);
        }
    };
    auto loadA = [&](half8* a, int k0) {
        a[0] = *(const half8*)(Arow0 + k0);
        a[1] = *(const half8*)(Arow1 + k0);
    };
    auto compute = [&](int buf, const half8* af) {
        half8 bf[NT];
#pragma unroll
        for (int nt = 0; nt < NT; ++nt) {
            const int n = wc + nt * 16 + l15;
            const int P = (n * 4 + (quad ^ (n & 3))) ^ (n & 4);
            bf[nt] = *(const half8*)&Bh[buf][P * 8];
        }
#pragma unroll
        for (int mt = 0; mt < 2; ++mt)
#pragma unroll
            for (int nt = 0; nt < NT; ++nt)
                acc[mt][nt] = __builtin_amdgcn_mfma_f32_16x16x32_f16(
                    af[mt], bf[nt], acc[mt][nt], 0, 0, 0);
    };

    const int NIT = K >> 5;   // 64 for K=2048
    half8 aE[2], aO[2];
    stageB(0, 0);
    stageB(1, 32);
    loadA(aE, 0);
    asm volatile("s_waitcnt vmcnt(0)" ::: "memory");
    __builtin_amdgcn_s_barrier();

    // main loop: it = 0 .. NIT-3 (62 iterations, even), unrolled x2 so the
    // A register double-buffer keeps static indices.
    for (int itb = 0; itb < NIT - 2; itb += 2) {
        // it = itb (even): consume aE, prefetch into aO
        loadA(aO, (itb + 1) * 32);
        stageB((itb + 2) & 3, (itb + 2) * 32);
        compute(itb & 3, aE);
        if constexpr (NT == 4) asm volatile("s_waitcnt vmcnt(2)" ::: "memory");
        else                   asm volatile("s_waitcnt vmcnt(1)" ::: "memory");
        __builtin_amdgcn_s_barrier();
        // it = itb+1 (odd): consume aO, prefetch into aE
        loadA(aE, (itb + 2) * 32);
        stageB((itb + 3) & 3, (itb + 3) * 32);
        compute((itb + 1) & 3, aO);
        if constexpr (NT == 4) asm volatile("s_waitcnt vmcnt(2)" ::: "memory");
        else                   asm volatile("s_waitcnt vmcnt(1)" ::: "memory");
        __builtin_amdgcn_s_barrier();
    }
    // it = NIT-2 (even -> aE current)
    loadA(aO, (NIT - 1) * 32);
    compute((NIT - 2) & 3, aE);
    asm volatile("s_waitcnt vmcnt(0)" ::: "memory");
    __builtin_amdgcn_s_barrier();
    compute((NIT - 1) & 3, aO);

#pragma unroll
    for (int mt = 0; mt < 2; ++mt)
#pragma unroll
        for (int nt = 0; nt < NT; ++nt) {
            const int c = n0 + wc + nt * 16 + l15;
#pragma unroll
            for (int reg = 0; reg < 4; ++reg) {
                const int r = m0 + wr + mt * 16 + quad * 4 + reg;
                C[(size_t)r * N + c] = (OutT)acc[mt][nt][reg];
            }
        }
}

// ---------------------------------------------------------------------------
// ba projection fused with gates + hidden fp32->fp16 side-product.
// ---------------------------------------------------------------------------
__global__ __launch_bounds__(256, 2) void gemm_ba_gates(const float* __restrict__ A,
                                                        const float* __restrict__ W,
                                                        const float* __restrict__ dt_bias,
                                                        const float* __restrict__ A_log,
                                                        float* __restrict__ lgd,
                                                        float* __restrict__ bet,
                                                        _Float16* __restrict__ hid_h) {
    const int m = blockIdx.x;
    const int tid = threadIdx.x;
    const int kl = tid & 31;
    const int ng = tid >> 5;
    const float* Arow = A + (size_t)m * 2048;
    __shared__ float sba[32];

    float4 a4[16];
#pragma unroll
    for (int j = 0; j < 16; ++j)
        a4[j] = *(const float4*)(Arow + j * 128 + kl * 4);

    if (ng == 0) {
#pragma unroll
        for (int j = 0; j < 16; ++j) {
            half4 h;
            h[0] = (_Float16)a4[j].x; h[1] = (_Float16)a4[j].y;
            h[2] = (_Float16)a4[j].z; h[3] = (_Float16)a4[j].w;
            *(half4*)&hid_h[(size_t)m * 2048 + j * 128 + kl * 4] = h;
        }
    }

#pragma unroll
    for (int nn = 0; nn < 4; ++nn) {
        const int n = nn * 8 + ng;
        const float* Wrow = W + (size_t)n * 2048;
        float acc = 0.f;
#pragma unroll
        for (int j = 0; j < 16; ++j) {
            const float4 w4 = *(const float4*)(Wrow + j * 128 + kl * 4);
            acc = fmaf(a4[j].x, w4.x, acc);
            acc = fmaf(a4[j].y, w4.y, acc);
            acc = fmaf(a4[j].z, w4.z, acc);
            acc = fmaf(a4[j].w, w4.w, acc);
        }
        acc += __shfl_xor(acc, 1, 64);
        acc += __shfl_xor(acc, 2, 64);
        acc += __shfl_xor(acc, 4, 64);
        acc += __shfl_xor(acc, 8, 64);
        acc += __shfl_xor(acc, 16, 64);
        if (kl == 0) sba[n] = acc;
    }
    __syncthreads();
    if (tid < 16) {
        const int vh = tid, kh = vh >> 1, r = vh & 1;
        const float b = sba[kh * 4 + r];
        const float a = sba[kh * 4 + 2 + r];
        bet[m * 16 + vh] = 1.f / (1.f + expf(-b));
        const float xx = a + dt_bias[vh];
        const float sp = (xx > 0.f) ? (xx + log1pf(expf(-xx))) : log1pf(expf(xx));
        lgd[m * 16 + vh] = -expf(A_log[vh]) * sp;
    }
}

// ---------------------------------------------------------------------------
// Depthwise causal conv1d (K=4) + SiLU + fused q/k L2-norm.
// ---------------------------------------------------------------------------
__global__ __launch_bounds__(512) void conv_silu_l2(const _Float16* __restrict__ qkvz,
                                                    const float* __restrict__ conv_w,
                                                    _Float16* __restrict__ qc,
                                                    _Float16* __restrict__ kc,
                                                    _Float16* __restrict__ vc) {
    const int t = blockIdx.x;
    const int c = threadIdx.x * 8;
    int col;
    _Float16* dst;
    bool isqk;
    float extra = 1.f;
    if (c < 1024) {
        col = ((c >> 7) * 768) + (c & 127);
        dst = qc + t * 1024 + c;
        isqk = true;
        extra = 0.08838834764831845f;
    } else if (c < 2048) {
        const int cc = c - 1024;
        col = ((cc >> 7) * 768) + 128 + (cc & 127);
        dst = kc + t * 1024 + cc;
        isqk = true;
    } else {
        const int cc = c - 2048;
        col = ((cc >> 8) * 768) + 256 + (cc & 255);
        dst = vc + (size_t)t * 2048 + cc;
        isqk = false;
    }
    const size_t gb = (size_t)t * QKVZ_N + col;
    const half8 x3 = *(const half8*)(qkvz + gb);
    half8 x2, x1, x0;
    if (t >= 1) x2 = *(const half8*)(qkvz + gb - QKVZ_N);
    if (t >= 2) x1 = *(const half8*)(qkvz + gb - 2 * (size_t)QKVZ_N);
    if (t >= 3) x0 = *(const half8*)(qkvz + gb - 3 * (size_t)QKVZ_N);

    float y[8];
    float ss = 0.f;
#pragma unroll
    for (int u = 0; u < 8; ++u) {
        const float4 wv = *(const float4*)(conv_w + (c + u) * 4);
        float acc = (float)x3[u] * wv.w;
        if (t >= 1) acc = fmaf((float)x2[u], wv.z, acc);
        if (t >= 2) acc = fmaf((float)x1[u], wv.y, acc);
        if (t >= 3) acc = fmaf((float)x0[u], wv.x, acc);
        acc = acc * (1.f / (1.f + expf(-acc)));   // silu
        y[u] = acc;
        ss = fmaf(acc, acc, ss);
    }
    half8 ov;
    if (isqk) {
        ss += __shfl_xor(ss, 1, 64);
        ss += __shfl_xor(ss, 2, 64);
        ss += __shfl_xor(ss, 4, 64);
        ss += __shfl_xor(ss, 8, 64);
        const float r = rsqrtf(ss + 1e-6f) * extra;
#pragma unroll
        for (int u = 0; u < 8; ++u) ov[u] = (_Float16)(y[u] * r);
    } else {
#pragma unroll
        for (int u = 0; u < 8; ++u) ov[u] = (_Float16)y[u];
    }
    *(half8*)dst = ov;
}

// ---------------------------------------------------------------------------
// chunk_prep: per (chunk c, v-head h), fully parallel (256 blocks).
// __launch_bounds__(256, 1): float x[64] must stay in registers (rule #20).
// ---------------------------------------------------------------------------
__global__ __launch_bounds__(256, 1) void chunk_prep(
    const _Float16* __restrict__ qch, const _Float16* __restrict__ kch,
    const _Float16* __restrict__ vch, const float* __restrict__ lgd,
    const float* __restrict__ bet, _Float16* __restrict__ CH,
    float* __restrict__ gamC) {
    const int blk = blockIdx.x;
    const int c = blk >> 4, h = blk & 15, kh = h >> 1;
    const int c0 = c * 64;
    const int tid = threadIdx.x, lane = tid & 63, wave = tid >> 6;
    const int l15 = lane & 15, quad = lane >> 4;

    __shared__ __align__(16) _Float16 Ksh[8192];
    __shared__ __align__(16) _Float16 Qsh[8192];
    __shared__ float Amat[64 * 65];
    __shared__ float Gs[64], Bets[64], Gam[64];

    {
        const int t = tid >> 2, kc0 = (tid & 3) * 4;
        const size_t gb = (size_t)(c0 + t) * 1024 + kh * 128;
#pragma unroll
        for (int i = 0; i < 4; ++i) {
            const int kc = kc0 + i;
            half8 kv = *(const half8*)(kch + gb + kc * 8);
            half8 qv = *(const half8*)(qch + gb + kc * 8);
            const int chl = t * 16 + (kc ^ (t & 15));
            *(half8*)&Ksh[chl * 8] = kv;
            *(half8*)&Qsh[chl * 8] = qv;
        }
    }
    if (tid < 64) {
        float g = lgd[(size_t)(c0 + tid) * 16 + h];
#pragma unroll
        for (int off = 1; off < 64; off <<= 1) {
            float y = __shfl_up(g, off, 64);
            if (tid >= off) g += y;
        }
        Gs[tid] = g;
        Gam[tid] = expf(g);
        Bets[tid] = bet[(size_t)(c0 + tid) * 16 + h];
    }
    __syncthreads();

    _Float16* CHb = CH + (size_t)(c * 16 + h) * 36864;
    _Float16* Ug = CHb;
    _Float16* Wtg = CHb + 8192;
    _Float16* Khg = CHb + 16384;
    _Float16* Qgg = CHb + 24576;
    _Float16* Lg = CHb + 32768;

    {
        floatx4 accKK[4], accQK[4];
#pragma unroll
        for (int tt = 0; tt < 4; ++tt) { accKK[tt] = 0; accQK[tt] = 0; }
        half8 bfK[4];
#pragma unroll
        for (int ks = 0; ks < 4; ++ks) {
            const int i = wave * 16 + l15;
            const int kc = ks * 4 + quad;
            bfK[ks] = *(const half8*)&Ksh[(i * 16 + (kc ^ (i & 15))) * 8];
        }
#pragma unroll
        for (int tt = 0; tt < 4; ++tt) {
            const int t = tt * 16 + l15;
#pragma unroll
            for (int ks = 0; ks < 4; ++ks) {
                const int kc = ks * 4 + quad;
                const int chl = (t * 16 + (kc ^ (t & 15))) * 8;
                half8 afK = *(const half8*)&Ksh[chl];
                half8 afQ = *(const half8*)&Qsh[chl];
                accKK[tt] = __builtin_amdgcn_mfma_f32_16x16x32_f16(afK, bfK[ks], accKK[tt], 0, 0, 0);
                accQK[tt] = __builtin_amdgcn_mfma_f32_16x16x32_f16(afQ, bfK[ks], accQK[tt], 0, 0, 0);
            }
        }
        const int ii = wave * 16 + l15;
        const float Gi = Gs[ii];
#pragma unroll
        for (int tt = 0; tt < 4; ++tt)
#pragma unroll
            for (int r = 0; r < 4; ++r) {
                const int t = tt * 16 + quad * 4 + r;
                const float Gt = Gs[t];
                const float ratio = (ii <= t) ? expf(Gt - Gi) : 0.f;
                if (ii < t) Amat[t * 65 + ii] = Bets[t] * ratio * accKK[tt][r];
                Lg[t * 64 + ii] = (_Float16)((ii <= t) ? ratio * accQK[tt][r] : 0.f);
            }
    }
    __syncthreads();

    {
        const int j = tid;
        float x[64];
        if (j < 128) {
#pragma unroll
            for (int t = 0; t < 64; ++t)
                x[t] = Bets[t] * (float)vch[(size_t)(c0 + t) * 2048 + h * 128 + j];
        } else {
            const int k = j - 128;
#pragma unroll
            for (int t = 0; t < 64; ++t) {
                const int chl = t * 16 + ((k >> 3) ^ (t & 15));
                x[t] = Bets[t] * Gam[t] * (float)Ksh[chl * 8 + (k & 7)];
            }
        }
#pragma unroll
        for (int t = 1; t < 64; ++t) {
            float acc = 0.f;
#pragma unroll
            for (int i = 0; i < t; ++i) acc = fmaf(Amat[t * 65 + i], x[i], acc);
            x[t] -= acc;
        }
        if (j < 128) {
#pragma unroll
            for (int t = 0; t < 64; t += 4) {
                half4 w4;
                w4[0] = (_Float16)x[t]; w4[1] = (_Float16)x[t + 1];
                w4[2] = (_Float16)x[t + 2]; w4[3] = (_Float16)x[t + 3];
                *(half4*)&Wtg[j * 64 + t] = w4;
            }
        } else {
            const int k = j - 128;
#pragma unroll
            for (int t = 0; t < 64; ++t) Ug[t * 128 + k] = (_Float16)x[t];
        }
    }

    {
        const float g63 = Gs[63];
        const int k = tid >> 1, cb = (tid & 1) * 32;
#pragma unroll
        for (int cc = 0; cc < 32; cc += 4) {
            half4 o4;
#pragma unroll
            for (int u = 0; u < 4; ++u) {
                const int ci = cb + cc + u;
                const int chl = ci * 16 + ((k >> 3) ^ (ci & 15));
                o4[u] = (_Float16)(expf(g63 - Gs[ci]) * (float)Ksh[chl * 8 + (k & 7)]);
            }
            *(half4*)&Khg[k * 64 + cb + cc] = o4;
        }
        const int cq = tid >> 2, kb = (tid & 3) * 4;
        const float gam = Gam[cq];
#pragma unroll
        for (int kc = 0; kc < 4; ++kc) {
            const int kcc = kb + kc;
            half8 q8 = *(const half8*)&Qsh[(cq * 16 + (kcc ^ (cq & 15))) * 8];
            half8 s8;
#pragma unroll
            for (int u = 0; u < 8; ++u) s8[u] = (_Float16)(gam * (float)q8[u]);
            *(half8*)&Qgg[cq * 128 + kcc * 8] = s8;
        }
        if (tid == 0) gamC[c * 16 + h] = Gam[63];
    }
}

// ---------------------------------------------------------------------------
// chunk_scan: 128 blocks (16 heads x 8 v-slices of 16), 256 threads.
// Waves split work; operands double-buffered global->VGPR; S^T/Dt in LDS.
// ---------------------------------------------------------------------------
struct ScanOps {
    half8 aU[4];
    half8 aQ[4];
    half8 aL[2];
    half8 aK[2][2];
    half4 wv;
    float gC;
};

__global__ __launch_bounds__(256) void chunk_scan(const _Float16* __restrict__ CH,
                                                  const float* __restrict__ gamC,
                                                  float* __restrict__ o) {
    const int h = blockIdx.x & 15;
    const int vsl = blockIdx.x >> 4;
    const int tid = threadIdx.x, lane = tid & 63, wave = tid >> 6;
    const int l15 = lane & 15, quad = lane >> 4;
    const int tw = wave * 16;
    const int kw = wave * 32;
    const int sKey = l15 << 1;
    const int dKey = (l15 << 1) & 14;

    __shared__ __align__(16) _Float16 Ssh[16 * 128];
    __shared__ __align__(16) _Float16 Dsh[16 * 64];

    *(half8*)&Ssh[tid * 8] = half8{0, 0, 0, 0, 0, 0, 0, 0};
    floatx4 Sacc[2];
    Sacc[0] = 0; Sacc[1] = 0;
    __syncthreads();

    auto loadOps = [&](ScanOps& S, int c) {
        const _Float16* CHb = CH + (size_t)(c * 16 + h) * 36864;
#pragma unroll
        for (int ks = 0; ks < 4; ++ks) {
            S.aU[ks] = *(const half8*)(CHb + (tw + l15) * 128 + ks * 32 + quad * 8);
            S.aQ[ks] = *(const half8*)(CHb + 24576 + (tw + l15) * 128 + ks * 32 + quad * 8);
        }
#pragma unroll
        for (int cs = 0; cs < 2; ++cs) {
            S.aL[cs] = *(const half8*)(CHb + 32768 + (tw + l15) * 64 + cs * 32 + quad * 8);
#pragma unroll
            for (int kt = 0; kt < 2; ++kt)
                S.aK[kt][cs] = *(const half8*)(CHb + 16384 + (kw + kt * 16 + l15) * 64 + cs * 32 + quad * 8);
        }
        S.wv = *(const half4*)(CHb + 8192 + (vsl * 16 + l15) * 64 + tw + quad * 4);
        S.gC = gamC[c * 16 + h];
    };

    auto chunkBody = [&](const ScanOps& S, int c) {
        half8 bs[4];
#pragma unroll
        for (int ks = 0; ks < 4; ++ks)
            bs[ks] = *(const half8*)&Ssh[(l15 * 32 + ((ks * 8 + quad * 2) ^ sKey)) * 4];
        floatx4 xa = {0.f, 0.f, 0.f, 0.f};
#pragma unroll
        for (int ks = 0; ks < 4; ++ks)
            xa = __builtin_amdgcn_mfma_f32_16x16x32_f16(S.aU[ks], bs[ks], xa, 0, 0, 0);
        half4 d4;
#pragma unroll
        for (int r = 0; r < 4; ++r) d4[r] = (_Float16)((float)S.wv[r] - xa[r]);
        *(half4*)&Dsh[(l15 * 16 + ((wave * 4 + quad) ^ dKey)) * 4] = d4;
        __syncthreads();

        half8 bd[2];
#pragma unroll
        for (int cs = 0; cs < 2; ++cs)
            bd[cs] = *(const half8*)&Dsh[(l15 * 16 + ((cs * 8 + quad * 2) ^ dKey)) * 4];
        floatx4 oacc = {0.f, 0.f, 0.f, 0.f};
#pragma unroll
        for (int ks = 0; ks < 4; ++ks)
            oacc = __builtin_amdgcn_mfma_f32_16x16x32_f16(S.aQ[ks], bs[ks], oacc, 0, 0, 0);
#pragma unroll
        for (int cs = 0; cs < 2; ++cs)
            oacc = __builtin_amdgcn_mfma_f32_16x16x32_f16(S.aL[cs], bd[cs], oacc, 0, 0, 0);
#pragma unroll
        for (int kt = 0; kt < 2; ++kt) {
#pragma unroll
            for (int r = 0; r < 4; ++r) Sacc[kt][r] *= S.gC;
#pragma unroll
            for (int cs = 0; cs < 2; ++cs)
                Sacc[kt] = __builtin_amdgcn_mfma_f32_16x16x32_f16(S.aK[kt][cs], bd[cs], Sacc[kt], 0, 0, 0);
        }
        const int col = h * 128 + vsl * 16 + l15;
#pragma unroll
        for (int r = 0; r < 4; ++r)
            o[(size_t)(c * 64 + tw + quad * 4 + r) * 2048 + col] = oacc[r];
#pragma unroll
        for (int kt = 0; kt < 2; ++kt) {
            half4 s4;
#pragma unroll
            for (int r = 0; r < 4; ++r) s4[r] = (_Float16)Sacc[kt][r];
            *(half4*)&Ssh[(l15 * 32 + ((wave * 8 + kt * 4 + quad) ^ sKey)) * 4] = s4;
        }
        __syncthreads();
    };

    ScanOps A_, B_;
    loadOps(A_, 0);
#pragma unroll 1
    for (int cc = 0; cc < 16; cc += 2) {
        loadOps(B_, cc + 1);
        chunkBody(A_, cc);
        if (cc + 2 < 16) loadOps(A_, cc + 2);
        chunkBody(B_, cc + 1);
    }
}

// ---------------------------------------------------------------------------
// Gated RMSNorm: xf = o * silu(z); xn = xf * rsqrt(mean(xf^2)+eps) * w
// ---------------------------------------------------------------------------
__global__ __launch_bounds__(64) void gated_norm(const float* __restrict__ o,
                                                 const _Float16* __restrict__ qkvz,
                                                 const float* __restrict__ nw,
                                                 _Float16* __restrict__ xn) {
    const int b = blockIdx.x;
    const int t = b >> 4;
    const int vh = b & 15;
    const int kh = vh >> 1;
    const int r = vh & 1;
    const float* op = o + (size_t)t * 2048 + vh * 128;
    const _Float16* zp = qkvz + (size_t)t * QKVZ_N + kh * 768 + 512 + r * 128;
    const int j = threadIdx.x * 2;
    const float2 ov = *(const float2*)(op + j);
    const half2t zv = *(const half2t*)(zp + j);
    const float z0 = (float)zv[0], z1 = (float)zv[1];
    const float f0 = ov.x * z0 / (1.f + expf(-z0));
    const float f1 = ov.y * z1 / (1.f + expf(-z1));
    float ss = f0 * f0 + f1 * f1;
#pragma unroll
    for (int m = 1; m < 64; m <<= 1) ss += __shfl_xor(ss, m, 64);
    const float rs = rsqrtf(ss * (1.f / 128.f) + 1e-6f);
    _Float16* xp = xn + (size_t)t * 2048 + vh * 128;
    half2t y;
    y[0] = (_Float16)(f0 * rs * nw[j]);
    y[1] = (_Float16)(f1 * rs * nw[j + 1]);
    *(half2t*)(xp + j) = y;
}

// ---------------------------------------------------------------------------
extern "C" void kernel_launch(void* const* d_in, const int* in_sizes, int n_in,
                              void* d_out, int out_size, void* d_ws, size_t ws_size,
                              hipStream_t stream) {
    const float* hidden  = (const float*)d_in[0];
    const float* w_qkvz  = (const float*)d_in[1];
    const float* w_ba    = (const float*)d_in[2];
    const float* conv_w  = (const float*)d_in[3];
    const float* dt_bias = (const float*)d_in[4];
    const float* A_log   = (const float*)d_in[5];
    const float* norm_w  = (const float*)d_in[6];
    const float* w_out   = (const float*)d_in[7];
    float* out = (float*)d_out;

    // workspace layout (~63.2 MB), lifetime-based overlaps:
    //   hidden_h overlaps o        (hidden_h dead after qkvz GEMM)
    //   CH + xn_h overlap wqkvz_h  (wqkvz_h dead after qkvz GEMM)
    char* w = (char*)d_ws;
    _Float16*  qkvz_h = (_Float16*)(w);                 // 12,582,912 B (fp16)
    _Float16*  qch    = (_Float16*)(w + 12713984);      //  2,097,152 B
    _Float16*  kch    = (_Float16*)(w + 14811136);      //  2,097,152 B
    _Float16*  vch    = (_Float16*)(w + 16908288);      //  4,194,304 B
    float*     lgd    = (float*)(w + 21102592);         //     65,536 B
    float*     bet    = (float*)(w + 21168128);         //     65,536 B
    float*     gamC   = (float*)(w + 21233664);         //      4,096 B
    float*     o      = (float*)(w + 21237760);         //  8,388,608 B
    _Float16*  hid_h  = (_Float16*)(w + 21237760);      //  overlaps o
    _Float16*  wqk_h  = (_Float16*)(w + 29626368);      // 25,165,824 B
    _Float16*  CH     = (_Float16*)(w + 29626368);      //  overlaps wqk_h
    _Float16*  xn_h   = (_Float16*)(w + 29626368 + 18874368);  // after CH
    _Float16*  wout_h = (_Float16*)(w + 54792192);      //  8,388,608 B

    const int n1 = QKVZ_N * HIDDEN / 4;      // 3,145,728 float4s
    const int n2 = VAL_DIM * HIDDEN / 4;     // 1,048,576
    cvt2<<<(n1 + n2 + 255) / 256, 256, 0, stream>>>(w_qkvz, wqk_h, n1,
                                                    w_out, wout_h, n2);
    gemm_ba_gates<<<T_LEN, 256, 0, stream>>>(hidden, w_ba, dt_bias, A_log,
                                             lgd, bet, hid_h);
    gemm_h16<4, _Float16><<<16 * 48, 256, 0, stream>>>(hid_h, wqk_h, qkvz_h, 16, 48, HIDDEN);
    conv_silu_l2<<<T_LEN, 512, 0, stream>>>(qkvz_h, conv_w, qch, kch, vch);
    chunk_prep<<<256, 256, 0, stream>>>(qch, kch, vch, lgd, bet, CH, gamC);
    chunk_scan<<<128, 256, 0, stream>>>(CH, gamC, o);
    gated_norm<<<T_LEN * 16, 64, 0, stream>>>(o, qkvz_h, norm_w, xn_h);
    gemm_h16<2, float><<<16 * 32, 256, 0, stream>>>(xn_h, wout_h, out, 16, 32, HIDDEN);
}

// Round 8
// 296.902 us; speedup vs baseline: 1.0951x; 1.0951x over previous
//
#include <hip/hip_runtime.h>
#include <math.h>

// ---------------- problem constants ----------------
#define T_LEN   1024
#define HIDDEN  2048
#define QKVZ_N  6144   // 2*KEY_DIM + 2*VALUE_DIM
#define VAL_DIM 2048

typedef _Float16 half8 __attribute__((ext_vector_type(8)));
typedef _Float16 half4 __attribute__((ext_vector_type(4)));
typedef _Float16 half2t __attribute__((ext_vector_type(2)));
typedef float floatx4 __attribute__((ext_vector_type(4)));

__device__ __forceinline__ float sigmoidf_(float x) { return 1.f / (1.f + expf(-x)); }

// async global->LDS, 16B per lane; LDS dest = wave-uniform base + lane*16
__device__ __forceinline__ void gl_lds16(const _Float16* g, _Float16* l) {
    __builtin_amdgcn_global_load_lds(
        (const __attribute__((address_space(1))) void*)g,
        (__attribute__((address_space(3))) void*)l, 16, 0, 0);
}

// ---------------------------------------------------------------------------
// fp32 -> fp16 bulk convert of the two weight matrices (hidden is converted
// as a side-product of gemm_ba_gates, which reads it anyway).
// ---------------------------------------------------------------------------
__global__ __launch_bounds__(256) void cvt2(const float* __restrict__ s1, _Float16* __restrict__ d1, int n1,
                                            const float* __restrict__ s2, _Float16* __restrict__ d2, int n2) {
    int i = blockIdx.x * 256 + threadIdx.x;
    const float* s;
    _Float16* d;
    if (i < n1) { s = s1; d = d1; }
    else if (i < n1 + n2) { s = s2; d = d2; i -= n1; }
    else return;
    const float4 v = ((const float4*)s)[i];
    half4 h;
    h[0] = (_Float16)v.x; h[1] = (_Float16)v.y;
    h[2] = (_Float16)v.z; h[3] = (_Float16)v.w;
    *(half4*)&d[i * 4] = h;
}

// ---------------------------------------------------------------------------
// qkvz GEMM: m97 geometry (guide §5 ladder: 64²=343, 128²=912 TF at this
// 2-barrier structure -- tile size is THE lever, measured).  128x128 tile,
// BK=32, 4 waves each 64x64 (4x4 frags of 16x16x32), double-buffered
// gl_lds16 staging (8KB A + 8KB B per buffer, 32KB total), ONE
// __syncthreads per iter (its vmcnt(0) drain = next tile's readiness).
// Per wave-iter: 4 gl_lds16, 8 ds_read_b128, 16 MFMA -- 2x the per-barrier
// MFMA density and 1.5x the FLOP/LDS-byte of the old 64x128 tile.
// R6's A-direct experiment is REVERTED: it put a fresh L2-latency register
// dependency on every iteration tail (47->69us, MfmaUtil 21->14).
// Swizzle (both sides, rule #21): logical (row r, 16B-chunk kq) lives at
// physical slot P = (r*4 + (kq^(r&3))) ^ (r&4).  Staging decodes (r,kq)
// from the physical slot p = base+lane:  r = (p>>2) ^ ((p>>4)&1),
// kq = (p&3) ^ (r&3)  (verified involution; bijective over 512 slots).
// Reads: 16 same-quad lanes hit all 8 bank-groups 2x = free (m136).
// Grid 8x48 = 384 blocks, all co-resident (LDS 32KB -> up to 5/CU).
// ---------------------------------------------------------------------------
__global__ __launch_bounds__(256, 2) void gemm128(const _Float16* __restrict__ A,
                                                  const _Float16* __restrict__ W,
                                                  _Float16* __restrict__ C,
                                                  int MB, int NB, int K) {
    const int N = NB * 128;
    const int l = blockIdx.x;
    const int x = l & 7;
    const int tt = l >> 3;
    const int mb = tt % MB;
    const int nb = x + 8 * (tt / MB);
    const int m0 = mb * 128, n0 = nb * 128;

    const int t = threadIdx.x;
    const int wave = t >> 6;
    const int lane = t & 63;
    const int wr = (wave >> 1) * 64;
    const int wc = (wave & 1) * 64;
    const int l15 = lane & 15;
    const int quad = lane >> 4;

    __shared__ __align__(16) _Float16 Ah[2][4096];  // 128 rows x 32 k
    __shared__ __align__(16) _Float16 Bh[2][4096];

    floatx4 acc[4][4];
#pragma unroll
    for (int i = 0; i < 4; ++i)
#pragma unroll
        for (int j = 0; j < 4; ++j) acc[i][j] = 0;

    auto stage = [&](int buf, int k0) {
#pragma unroll
        for (int j = 0; j < 2; ++j) {
            const int p = (wave * 2 + j) * 64 + lane;     // physical slot
            const int r = (p >> 2) ^ ((p >> 4) & 1);      // logical row
            const int kq = (p & 3) ^ (r & 3);             // logical chunk
            gl_lds16(A + (size_t)(m0 + r) * K + k0 + kq * 8,
                     &Ah[buf][(wave * 2 + j) * 512]);
            gl_lds16(W + (size_t)(n0 + r) * K + k0 + kq * 8,
                     &Bh[buf][(wave * 2 + j) * 512]);
        }
    };

    auto compute = [&](int buf) {
        half8 af[4], bf[4];
#pragma unroll
        for (int mt = 0; mt < 4; ++mt) {
            const int m = wr + mt * 16 + l15;
            const int P = (m * 4 + (quad ^ (m & 3))) ^ (m & 4);
            af[mt] = *(const half8*)&Ah[buf][P * 8];
        }
#pragma unroll
        for (int nt = 0; nt < 4; ++nt) {
            const int n = wc + nt * 16 + l15;
            const int P = (n * 4 + (quad ^ (n & 3))) ^ (n & 4);
            bf[nt] = *(const half8*)&Bh[buf][P * 8];
        }
#pragma unroll
        for (int mt = 0; mt < 4; ++mt)
#pragma unroll
            for (int nt = 0; nt < 4; ++nt)
                acc[mt][nt] = __builtin_amdgcn_mfma_f32_16x16x32_f16(
                    af[mt], bf[nt], acc[mt][nt], 0, 0, 0);
    };

    const int NIT = K >> 5;   // 64
    stage(0, 0);
    __syncthreads();
    int cur = 0;
    for (int it = 0; it < NIT; ++it) {
        if (it + 1 < NIT) stage(cur ^ 1, (it + 1) * 32);
        compute(cur);
        if (it + 1 < NIT) {
            __syncthreads();
            cur ^= 1;
        }
    }
#pragma unroll
    for (int mt = 0; mt < 4; ++mt)
#pragma unroll
        for (int nt = 0; nt < 4; ++nt) {
            const int c = n0 + wc + nt * 16 + l15;
#pragma unroll
            for (int reg = 0; reg < 4; ++reg) {
                const int r = m0 + wr + mt * 16 + quad * 4 + reg;
                C[(size_t)r * N + c] = (_Float16)acc[mt][nt][reg];
            }
        }
}

// ---------------------------------------------------------------------------
// out GEMM (R4 template, A via LDS, 4 buffers, 2-ahead counted vmcnt):
// NT=2 (64x64), grid 16x32 = 512 = 2/CU, LDS 32KB.
// ---------------------------------------------------------------------------
template <int NT, typename OutT>
__global__ __launch_bounds__(256, 2) void gemm_h16(const _Float16* __restrict__ A,
                                                   const _Float16* __restrict__ W,
                                                   OutT* __restrict__ C,
                                                   int MB, int NB, int K) {
    const int BN = NT * 32;
    const int N = NB * BN;
    const int l = blockIdx.x;
    const int x = l & 7;
    const int tt = l >> 3;
    const int mb = tt % MB;
    const int nb = x + 8 * (tt / MB);
    const int m0 = mb * 64, n0 = nb * BN;

    const int t = threadIdx.x;
    const int wave = t >> 6;
    const int lane = t & 63;
    const int wr = (wave >> 1) * 32;
    const int wc = (wave & 1) * (NT * 16);
    const int l15 = lane & 15;
    const int quad = lane >> 4;

    __shared__ __align__(16) _Float16 Ah[4][64 * 32];
    __shared__ __align__(16) _Float16 Bh[4][BN * 32];

    const int Rl = lane >> 2, sl = lane & 3;

    floatx4 acc[2][NT];
#pragma unroll
    for (int i = 0; i < 2; ++i)
#pragma unroll
        for (int j = 0; j < NT; ++j) acc[i][j] = 0;

    auto stage = [&](int buf, int k0) {
        {
            const int R = wave * 16 + Rl;
            const int r = R ^ ((R >> 2) & 1);
            const int kq = sl ^ (r & 3);
            gl_lds16(A + (size_t)(m0 + r) * K + k0 + kq * 8,
                     &Ah[buf][wave * 512]);
        }
#pragma unroll
        for (int g = 0; g < NT / 2; ++g) {
            const int R = wave * (NT * 8) + g * 16 + Rl;
            const int r = R ^ ((R >> 2) & 1);
            const int kq = sl ^ (r & 3);
            gl_lds16(W + (size_t)(n0 + r) * K + k0 + kq * 8,
                     &Bh[buf][(wave * (NT / 2) + g) * 512]);
        }
    };

    auto compute = [&](int buf) {
        half8 af[2], bf[NT];
#pragma unroll
        for (int mt = 0; mt < 2; ++mt) {
            const int m = wr + mt * 16 + l15;
            const int P = (m * 4 + (quad ^ (m & 3))) ^ (m & 4);
            af[mt] = *(const half8*)&Ah[buf][P * 8];
        }
#pragma unroll
        for (int nt = 0; nt < NT; ++nt) {
            const int n = wc + nt * 16 + l15;
            const int P = (n * 4 + (quad ^ (n & 3))) ^ (n & 4);
            bf[nt] = *(const half8*)&Bh[buf][P * 8];
        }
#pragma unroll
        for (int mt = 0; mt < 2; ++mt)
#pragma unroll
            for (int nt = 0; nt < NT; ++nt)
                acc[mt][nt] = __builtin_amdgcn_mfma_f32_16x16x32_f16(
                    af[mt], bf[nt], acc[mt][nt], 0, 0, 0);
    };

    const int NIT = K >> 5;
    stage(0, 0);
    stage(1, 32);
    if constexpr (NT == 4) asm volatile("s_waitcnt vmcnt(3)" ::: "memory");
    else                   asm volatile("s_waitcnt vmcnt(2)" ::: "memory");
    __builtin_amdgcn_s_barrier();

    for (int it = 0; it < NIT - 2; ++it) {
        stage((it + 2) & 3, (it + 2) * 32);
        compute(it & 3);
        if constexpr (NT == 4) asm volatile("s_waitcnt vmcnt(3)" ::: "memory");
        else                   asm volatile("s_waitcnt vmcnt(2)" ::: "memory");
        __builtin_amdgcn_s_barrier();
    }
    compute((NIT - 2) & 3);
    asm volatile("s_waitcnt vmcnt(0)" ::: "memory");
    __builtin_amdgcn_s_barrier();
    compute((NIT - 1) & 3);

#pragma unroll
    for (int mt = 0; mt < 2; ++mt)
#pragma unroll
        for (int nt = 0; nt < NT; ++nt) {
            const int c = n0 + wc + nt * 16 + l15;
#pragma unroll
            for (int reg = 0; reg < 4; ++reg) {
                const int r = m0 + wr + mt * 16 + quad * 4 + reg;
                C[(size_t)r * N + c] = (OutT)acc[mt][nt][reg];
            }
        }
}

// ---------------------------------------------------------------------------
// ba projection fused with gates + hidden fp32->fp16 side-product.
// ---------------------------------------------------------------------------
__global__ __launch_bounds__(256, 2) void gemm_ba_gates(const float* __restrict__ A,
                                                        const float* __restrict__ W,
                                                        const float* __restrict__ dt_bias,
                                                        const float* __restrict__ A_log,
                                                        float* __restrict__ lgd,
                                                        float* __restrict__ bet,
                                                        _Float16* __restrict__ hid_h) {
    const int m = blockIdx.x;
    const int tid = threadIdx.x;
    const int kl = tid & 31;
    const int ng = tid >> 5;
    const float* Arow = A + (size_t)m * 2048;
    __shared__ float sba[32];

    float4 a4[16];
#pragma unroll
    for (int j = 0; j < 16; ++j)
        a4[j] = *(const float4*)(Arow + j * 128 + kl * 4);

    if (ng == 0) {
#pragma unroll
        for (int j = 0; j < 16; ++j) {
            half4 h;
            h[0] = (_Float16)a4[j].x; h[1] = (_Float16)a4[j].y;
            h[2] = (_Float16)a4[j].z; h[3] = (_Float16)a4[j].w;
            *(half4*)&hid_h[(size_t)m * 2048 + j * 128 + kl * 4] = h;
        }
    }

#pragma unroll
    for (int nn = 0; nn < 4; ++nn) {
        const int n = nn * 8 + ng;
        const float* Wrow = W + (size_t)n * 2048;
        float acc = 0.f;
#pragma unroll
        for (int j = 0; j < 16; ++j) {
            const float4 w4 = *(const float4*)(Wrow + j * 128 + kl * 4);
            acc = fmaf(a4[j].x, w4.x, acc);
            acc = fmaf(a4[j].y, w4.y, acc);
            acc = fmaf(a4[j].z, w4.z, acc);
            acc = fmaf(a4[j].w, w4.w, acc);
        }
        acc += __shfl_xor(acc, 1, 64);
        acc += __shfl_xor(acc, 2, 64);
        acc += __shfl_xor(acc, 4, 64);
        acc += __shfl_xor(acc, 8, 64);
        acc += __shfl_xor(acc, 16, 64);
        if (kl == 0) sba[n] = acc;
    }
    __syncthreads();
    if (tid < 16) {
        const int vh = tid, kh = vh >> 1, r = vh & 1;
        const float b = sba[kh * 4 + r];
        const float a = sba[kh * 4 + 2 + r];
        bet[m * 16 + vh] = 1.f / (1.f + expf(-b));
        const float xx = a + dt_bias[vh];
        const float sp = (xx > 0.f) ? (xx + log1pf(expf(-xx))) : log1pf(expf(xx));
        lgd[m * 16 + vh] = -expf(A_log[vh]) * sp;
    }
}

// ---------------------------------------------------------------------------
// Depthwise causal conv1d (K=4) + SiLU + fused q/k L2-norm.
// ---------------------------------------------------------------------------
__global__ __launch_bounds__(512) void conv_silu_l2(const _Float16* __restrict__ qkvz,
                                                    const float* __restrict__ conv_w,
                                                    _Float16* __restrict__ qc,
                                                    _Float16* __restrict__ kc,
                                                    _Float16* __restrict__ vc) {
    const int t = blockIdx.x;
    const int c = threadIdx.x * 8;
    int col;
    _Float16* dst;
    bool isqk;
    float extra = 1.f;
    if (c < 1024) {
        col = ((c >> 7) * 768) + (c & 127);
        dst = qc + t * 1024 + c;
        isqk = true;
        extra = 0.08838834764831845f;
    } else if (c < 2048) {
        const int cc = c - 1024;
        col = ((cc >> 7) * 768) + 128 + (cc & 127);
        dst = kc + t * 1024 + cc;
        isqk = true;
    } else {
        const int cc = c - 2048;
        col = ((cc >> 8) * 768) + 256 + (cc & 255);
        dst = vc + (size_t)t * 2048 + cc;
        isqk = false;
    }
    const size_t gb = (size_t)t * QKVZ_N + col;
    const half8 x3 = *(const half8*)(qkvz + gb);
    half8 x2, x1, x0;
    if (t >= 1) x2 = *(const half8*)(qkvz + gb - QKVZ_N);
    if (t >= 2) x1 = *(const half8*)(qkvz + gb - 2 * (size_t)QKVZ_N);
    if (t >= 3) x0 = *(const half8*)(qkvz + gb - 3 * (size_t)QKVZ_N);

    float y[8];
    float ss = 0.f;
#pragma unroll
    for (int u = 0; u < 8; ++u) {
        const float4 wv = *(const float4*)(conv_w + (c + u) * 4);
        float acc = (float)x3[u] * wv.w;
        if (t >= 1) acc = fmaf((float)x2[u], wv.z, acc);
        if (t >= 2) acc = fmaf((float)x1[u], wv.y, acc);
        if (t >= 3) acc = fmaf((float)x0[u], wv.x, acc);
        acc = acc * (1.f / (1.f + expf(-acc)));   // silu
        y[u] = acc;
        ss = fmaf(acc, acc, ss);
    }
    half8 ov;
    if (isqk) {
        ss += __shfl_xor(ss, 1, 64);
        ss += __shfl_xor(ss, 2, 64);
        ss += __shfl_xor(ss, 4, 64);
        ss += __shfl_xor(ss, 8, 64);
        const float r = rsqrtf(ss + 1e-6f) * extra;
#pragma unroll
        for (int u = 0; u < 8; ++u) ov[u] = (_Float16)(y[u] * r);
    } else {
#pragma unroll
        for (int u = 0; u < 8; ++u) ov[u] = (_Float16)y[u];
    }
    *(half8*)dst = ov;
}

// ---------------------------------------------------------------------------
// chunk_prep: per (chunk c, v-head h), fully parallel (256 blocks).
// __launch_bounds__(256, 1): float x[64] must stay in registers (rule #20).
// ---------------------------------------------------------------------------
__global__ __launch_bounds__(256, 1) void chunk_prep(
    const _Float16* __restrict__ qch, const _Float16* __restrict__ kch,
    const _Float16* __restrict__ vch, const float* __restrict__ lgd,
    const float* __restrict__ bet, _Float16* __restrict__ CH,
    float* __restrict__ gamC) {
    const int blk = blockIdx.x;
    const int c = blk >> 4, h = blk & 15, kh = h >> 1;
    const int c0 = c * 64;
    const int tid = threadIdx.x, lane = tid & 63, wave = tid >> 6;
    const int l15 = lane & 15, quad = lane >> 4;

    __shared__ __align__(16) _Float16 Ksh[8192];
    __shared__ __align__(16) _Float16 Qsh[8192];
    __shared__ float Amat[64 * 65];
    __shared__ float Gs[64], Bets[64], Gam[64];

    {
        const int t = tid >> 2, kc0 = (tid & 3) * 4;
        const size_t gb = (size_t)(c0 + t) * 1024 + kh * 128;
#pragma unroll
        for (int i = 0; i < 4; ++i) {
            const int kc = kc0 + i;
            half8 kv = *(const half8*)(kch + gb + kc * 8);
            half8 qv = *(const half8*)(qch + gb + kc * 8);
            const int chl = t * 16 + (kc ^ (t & 15));
            *(half8*)&Ksh[chl * 8] = kv;
            *(half8*)&Qsh[chl * 8] = qv;
        }
    }
    if (tid < 64) {
        float g = lgd[(size_t)(c0 + tid) * 16 + h];
#pragma unroll
        for (int off = 1; off < 64; off <<= 1) {
            float y = __shfl_up(g, off, 64);
            if (tid >= off) g += y;
        }
        Gs[tid] = g;
        Gam[tid] = expf(g);
        Bets[tid] = bet[(size_t)(c0 + tid) * 16 + h];
    }
    __syncthreads();

    _Float16* CHb = CH + (size_t)(c * 16 + h) * 36864;
    _Float16* Ug = CHb;
    _Float16* Wtg = CHb + 8192;
    _Float16* Khg = CHb + 16384;
    _Float16* Qgg = CHb + 24576;
    _Float16* Lg = CHb + 32768;

    {
        floatx4 accKK[4], accQK[4];
#pragma unroll
        for (int tt = 0; tt < 4; ++tt) { accKK[tt] = 0; accQK[tt] = 0; }
        half8 bfK[4];
#pragma unroll
        for (int ks = 0; ks < 4; ++ks) {
            const int i = wave * 16 + l15;
            const int kc = ks * 4 + quad;
            bfK[ks] = *(const half8*)&Ksh[(i * 16 + (kc ^ (i & 15))) * 8];
        }
#pragma unroll
        for (int tt = 0; tt < 4; ++tt) {
            const int t = tt * 16 + l15;
#pragma unroll
            for (int ks = 0; ks < 4; ++ks) {
                const int kc = ks * 4 + quad;
                const int chl = (t * 16 + (kc ^ (t & 15))) * 8;
                half8 afK = *(const half8*)&Ksh[chl];
                half8 afQ = *(const half8*)&Qsh[chl];
                accKK[tt] = __builtin_amdgcn_mfma_f32_16x16x32_f16(afK, bfK[ks], accKK[tt], 0, 0, 0);
                accQK[tt] = __builtin_amdgcn_mfma_f32_16x16x32_f16(afQ, bfK[ks], accQK[tt], 0, 0, 0);
            }
        }
        const int ii = wave * 16 + l15;
        const float Gi = Gs[ii];
#pragma unroll
        for (int tt = 0; tt < 4; ++tt)
#pragma unroll
            for (int r = 0; r < 4; ++r) {
                const int t = tt * 16 + quad * 4 + r;
                const float Gt = Gs[t];
                const float ratio = (ii <= t) ? expf(Gt - Gi) : 0.f;
                if (ii < t) Amat[t * 65 + ii] = Bets[t] * ratio * accKK[tt][r];
                Lg[t * 64 + ii] = (_Float16)((ii <= t) ? ratio * accQK[tt][r] : 0.f);
            }
    }
    __syncthreads();

    {
        const int j = tid;
        float x[64];
        if (j < 128) {
#pragma unroll
            for (int t = 0; t < 64; ++t)
                x[t] = Bets[t] * (float)vch[(size_t)(c0 + t) * 2048 + h * 128 + j];
        } else {
            const int k = j - 128;
#pragma unroll
            for (int t = 0; t < 64; ++t) {
                const int chl = t * 16 + ((k >> 3) ^ (t & 15));
                x[t] = Bets[t] * Gam[t] * (float)Ksh[chl * 8 + (k & 7)];
            }
        }
#pragma unroll
        for (int t = 1; t < 64; ++t) {
            float acc = 0.f;
#pragma unroll
            for (int i = 0; i < t; ++i) acc = fmaf(Amat[t * 65 + i], x[i], acc);
            x[t] -= acc;
        }
        if (j < 128) {
#pragma unroll
            for (int t = 0; t < 64; t += 4) {
                half4 w4;
                w4[0] = (_Float16)x[t]; w4[1] = (_Float16)x[t + 1];
                w4[2] = (_Float16)x[t + 2]; w4[3] = (_Float16)x[t + 3];
                *(half4*)&Wtg[j * 64 + t] = w4;
            }
        } else {
            const int k = j - 128;
#pragma unroll
            for (int t = 0; t < 64; ++t) Ug[t * 128 + k] = (_Float16)x[t];
        }
    }

    {
        const float g63 = Gs[63];
        const int k = tid >> 1, cb = (tid & 1) * 32;
#pragma unroll
        for (int cc = 0; cc < 32; cc += 4) {
            half4 o4;
#pragma unroll
            for (int u = 0; u < 4; ++u) {
                const int ci = cb + cc + u;
                const int chl = ci * 16 + ((k >> 3) ^ (ci & 15));
                o4[u] = (_Float16)(expf(g63 - Gs[ci]) * (float)Ksh[chl * 8 + (k & 7)]);
            }
            *(half4*)&Khg[k * 64 + cb + cc] = o4;
        }
        const int cq = tid >> 2, kb = (tid & 3) * 4;
        const float gam = Gam[cq];
#pragma unroll
        for (int kc = 0; kc < 4; ++kc) {
            const int kcc = kb + kc;
            half8 q8 = *(const half8*)&Qsh[(cq * 16 + (kcc ^ (cq & 15))) * 8];
            half8 s8;
#pragma unroll
            for (int u = 0; u < 8; ++u) s8[u] = (_Float16)(gam * (float)q8[u]);
            *(half8*)&Qgg[cq * 128 + kcc * 8] = s8;
        }
        if (tid == 0) gamC[c * 16 + h] = Gam[63];
    }
}

// ---------------------------------------------------------------------------
// chunk_scan: 128 blocks (16 heads x 8 v-slices of 16), 256 threads.
// Waves split work; operands double-buffered global->VGPR; S^T/Dt in LDS.
// ---------------------------------------------------------------------------
struct ScanOps {
    half8 aU[4];
    half8 aQ[4];
    half8 aL[2];
    half8 aK[2][2];
    half4 wv;
    float gC;
};

__global__ __launch_bounds__(256) void chunk_scan(const _Float16* __restrict__ CH,
                                                  const float* __restrict__ gamC,
                                                  float* __restrict__ o) {
    const int h = blockIdx.x & 15;
    const int vsl = blockIdx.x >> 4;
    const int tid = threadIdx.x, lane = tid & 63, wave = tid >> 6;
    const int l15 = lane & 15, quad = lane >> 4;
    const int tw = wave * 16;
    const int kw = wave * 32;
    const int sKey = l15 << 1;
    const int dKey = (l15 << 1) & 14;

    __shared__ __align__(16) _Float16 Ssh[16 * 128];
    __shared__ __align__(16) _Float16 Dsh[16 * 64];

    *(half8*)&Ssh[tid * 8] = half8{0, 0, 0, 0, 0, 0, 0, 0};
    floatx4 Sacc[2];
    Sacc[0] = 0; Sacc[1] = 0;
    __syncthreads();

    auto loadOps = [&](ScanOps& S, int c) {
        const _Float16* CHb = CH + (size_t)(c * 16 + h) * 36864;
#pragma unroll
        for (int ks = 0; ks < 4; ++ks) {
            S.aU[ks] = *(const half8*)(CHb + (tw + l15) * 128 + ks * 32 + quad * 8);
            S.aQ[ks] = *(const half8*)(CHb + 24576 + (tw + l15) * 128 + ks * 32 + quad * 8);
        }
#pragma unroll
        for (int cs = 0; cs < 2; ++cs) {
            S.aL[cs] = *(const half8*)(CHb + 32768 + (tw + l15) * 64 + cs * 32 + quad * 8);
#pragma unroll
            for (int kt = 0; kt < 2; ++kt)
                S.aK[kt][cs] = *(const half8*)(CHb + 16384 + (kw + kt * 16 + l15) * 64 + cs * 32 + quad * 8);
        }
        S.wv = *(const half4*)(CHb + 8192 + (vsl * 16 + l15) * 64 + tw + quad * 4);
        S.gC = gamC[c * 16 + h];
    };

    auto chunkBody = [&](const ScanOps& S, int c) {
        half8 bs[4];
#pragma unroll
        for (int ks = 0; ks < 4; ++ks)
            bs[ks] = *(const half8*)&Ssh[(l15 * 32 + ((ks * 8 + quad * 2) ^ sKey)) * 4];
        floatx4 xa = {0.f, 0.f, 0.f, 0.f};
#pragma unroll
        for (int ks = 0; ks < 4; ++ks)
            xa = __builtin_amdgcn_mfma_f32_16x16x32_f16(S.aU[ks], bs[ks], xa, 0, 0, 0);
        half4 d4;
#pragma unroll
        for (int r = 0; r < 4; ++r) d4[r] = (_Float16)((float)S.wv[r] - xa[r]);
        *(half4*)&Dsh[(l15 * 16 + ((wave * 4 + quad) ^ dKey)) * 4] = d4;
        __syncthreads();

        half8 bd[2];
#pragma unroll
        for (int cs = 0; cs < 2; ++cs)
            bd[cs] = *(const half8*)&Dsh[(l15 * 16 + ((cs * 8 + quad * 2) ^ dKey)) * 4];
        floatx4 oacc = {0.f, 0.f, 0.f, 0.f};
#pragma unroll
        for (int ks = 0; ks < 4; ++ks)
            oacc = __builtin_amdgcn_mfma_f32_16x16x32_f16(S.aQ[ks], bs[ks], oacc, 0, 0, 0);
#pragma unroll
        for (int cs = 0; cs < 2; ++cs)
            oacc = __builtin_amdgcn_mfma_f32_16x16x32_f16(S.aL[cs], bd[cs], oacc, 0, 0, 0);
#pragma unroll
        for (int kt = 0; kt < 2; ++kt) {
#pragma unroll
            for (int r = 0; r < 4; ++r) Sacc[kt][r] *= S.gC;
#pragma unroll
            for (int cs = 0; cs < 2; ++cs)
                Sacc[kt] = __builtin_amdgcn_mfma_f32_16x16x32_f16(S.aK[kt][cs], bd[cs], Sacc[kt], 0, 0, 0);
        }
        const int col = h * 128 + vsl * 16 + l15;
#pragma unroll
        for (int r = 0; r < 4; ++r)
            o[(size_t)(c * 64 + tw + quad * 4 + r) * 2048 + col] = oacc[r];
#pragma unroll
        for (int kt = 0; kt < 2; ++kt) {
            half4 s4;
#pragma unroll
            for (int r = 0; r < 4; ++r) s4[r] = (_Float16)Sacc[kt][r];
            *(half4*)&Ssh[(l15 * 32 + ((wave * 8 + kt * 4 + quad) ^ sKey)) * 4] = s4;
        }
        __syncthreads();
    };

    ScanOps A_, B_;
    loadOps(A_, 0);
#pragma unroll 1
    for (int cc = 0; cc < 16; cc += 2) {
        loadOps(B_, cc + 1);
        chunkBody(A_, cc);
        if (cc + 2 < 16) loadOps(A_, cc + 2);
        chunkBody(B_, cc + 1);
    }
}

// ---------------------------------------------------------------------------
// Gated RMSNorm: xf = o * silu(z); xn = xf * rsqrt(mean(xf^2)+eps) * w
// ---------------------------------------------------------------------------
__global__ __launch_bounds__(64) void gated_norm(const float* __restrict__ o,
                                                 const _Float16* __restrict__ qkvz,
                                                 const float* __restrict__ nw,
                                                 _Float16* __restrict__ xn) {
    const int b = blockIdx.x;
    const int t = b >> 4;
    const int vh = b & 15;
    const int kh = vh >> 1;
    const int r = vh & 1;
    const float* op = o + (size_t)t * 2048 + vh * 128;
    const _Float16* zp = qkvz + (size_t)t * QKVZ_N + kh * 768 + 512 + r * 128;
    const int j = threadIdx.x * 2;
    const float2 ov = *(const float2*)(op + j);
    const half2t zv = *(const half2t*)(zp + j);
    const float z0 = (float)zv[0], z1 = (float)zv[1];
    const float f0 = ov.x * z0 / (1.f + expf(-z0));
    const float f1 = ov.y * z1 / (1.f + expf(-z1));
    float ss = f0 * f0 + f1 * f1;
#pragma unroll
    for (int m = 1; m < 64; m <<= 1) ss += __shfl_xor(ss, m, 64);
    const float rs = rsqrtf(ss * (1.f / 128.f) + 1e-6f);
    _Float16* xp = xn + (size_t)t * 2048 + vh * 128;
    half2t y;
    y[0] = (_Float16)(f0 * rs * nw[j]);
    y[1] = (_Float16)(f1 * rs * nw[j + 1]);
    *(half2t*)(xp + j) = y;
}

// ---------------------------------------------------------------------------
extern "C" void kernel_launch(void* const* d_in, const int* in_sizes, int n_in,
                              void* d_out, int out_size, void* d_ws, size_t ws_size,
                              hipStream_t stream) {
    const float* hidden  = (const float*)d_in[0];
    const float* w_qkvz  = (const float*)d_in[1];
    const float* w_ba    = (const float*)d_in[2];
    const float* conv_w  = (const float*)d_in[3];
    const float* dt_bias = (const float*)d_in[4];
    const float* A_log   = (const float*)d_in[5];
    const float* norm_w  = (const float*)d_in[6];
    const float* w_out   = (const float*)d_in[7];
    float* out = (float*)d_out;

    // workspace layout (~63.2 MB), lifetime-based overlaps:
    //   hidden_h overlaps o        (hidden_h dead after qkvz GEMM)
    //   CH + xn_h overlap wqkvz_h  (wqkvz_h dead after qkvz GEMM)
    char* w = (char*)d_ws;
    _Float16*  qkvz_h = (_Float16*)(w);                 // 12,582,912 B (fp16)
    _Float16*  qch    = (_Float16*)(w + 12713984);      //  2,097,152 B
    _Float16*  kch    = (_Float16*)(w + 14811136);      //  2,097,152 B
    _Float16*  vch    = (_Float16*)(w + 16908288);      //  4,194,304 B
    float*     lgd    = (float*)(w + 21102592);         //     65,536 B
    float*     bet    = (float*)(w + 21168128);         //     65,536 B
    float*     gamC   = (float*)(w + 21233664);         //      4,096 B
    float*     o      = (float*)(w + 21237760);         //  8,388,608 B
    _Float16*  hid_h  = (_Float16*)(w + 21237760);      //  overlaps o
    _Float16*  wqk_h  = (_Float16*)(w + 29626368);      // 25,165,824 B
    _Float16*  CH     = (_Float16*)(w + 29626368);      //  overlaps wqk_h
    _Float16*  xn_h   = (_Float16*)(w + 29626368 + 18874368);  // after CH
    _Float16*  wout_h = (_Float16*)(w + 54792192);      //  8,388,608 B

    const int n1 = QKVZ_N * HIDDEN / 4;      // 3,145,728 float4s
    const int n2 = VAL_DIM * HIDDEN / 4;     // 1,048,576
    cvt2<<<(n1 + n2 + 255) / 256, 256, 0, stream>>>(w_qkvz, wqk_h, n1,
                                                    w_out, wout_h, n2);
    gemm_ba_gates<<<T_LEN, 256, 0, stream>>>(hidden, w_ba, dt_bias, A_log,
                                             lgd, bet, hid_h);
    gemm128<<<8 * 48, 256, 0, stream>>>(hid_h, wqk_h, qkvz_h, 8, 48, HIDDEN);
    conv_silu_l2<<<T_LEN, 512, 0, stream>>>(qkvz_h, conv_w, qch, kch, vch);
    chunk_prep<<<256, 256, 0, stream>>>(qch, kch, vch, lgd, bet, CH, gamC);
    chunk_scan<<<128, 256, 0, stream>>>(CH, gamC, o);
    gated_norm<<<T_LEN * 16, 64, 0, stream>>>(o, qkvz_h, norm_w, xn_h);
    gemm_h16<2, float><<<16 * 32, 256, 0, stream>>>(xn_h, wout_h, out, 16, 32, HIDDEN);
}

// Round 9
// 288.417 us; speedup vs baseline: 1.1273x; 1.0294x over previous
//
#include <hip/hip_runtime.h>
#include <math.h>

// ---------------- problem constants ----------------
#define T_LEN   1024
#define HIDDEN  2048
#define QKVZ_N  6144   // 2*KEY_DIM + 2*VALUE_DIM
#define VAL_DIM 2048

typedef _Float16 half8 __attribute__((ext_vector_type(8)));
typedef _Float16 half4 __attribute__((ext_vector_type(4)));
typedef _Float16 half2t __attribute__((ext_vector_type(2)));
typedef float floatx4 __attribute__((ext_vector_type(4)));

__device__ __forceinline__ float sigmoidf_(float x) { return 1.f / (1.f + expf(-x)); }

// async global->LDS, 16B per lane; LDS dest = wave-uniform base + lane*16
__device__ __forceinline__ void gl_lds16(const _Float16* g, _Float16* l) {
    __builtin_amdgcn_global_load_lds(
        (const __attribute__((address_space(1))) void*)g,
        (__attribute__((address_space(3))) void*)l, 16, 0, 0);
}

// ---------------------------------------------------------------------------
// fused fp32 -> fp16 bulk convert of the three GEMM operands (1 launch)
// (R3 configuration restored: best-measured total 286.8us)
// ---------------------------------------------------------------------------
__global__ __launch_bounds__(256) void cvt3(const float* __restrict__ s0, _Float16* __restrict__ d0, int n0,
                                            const float* __restrict__ s1, _Float16* __restrict__ d1, int n1,
                                            const float* __restrict__ s2, _Float16* __restrict__ d2, int n2) {
    int i = blockIdx.x * 256 + threadIdx.x;
    const float* s;
    _Float16* d;
    if (i < n0) { s = s0; d = d0; }
    else if (i < n0 + n1) { s = s1; d = d1; i -= n0; }
    else if (i < n0 + n1 + n2) { s = s2; d = d2; i -= n0 + n1; }
    else return;
    const float4 v = ((const float4*)s)[i];
    half4 h;
    h[0] = (_Float16)v.x; h[1] = (_Float16)v.y;
    h[2] = (_Float16)v.z; h[3] = (_Float16)v.w;
    *(half4*)&d[i * 4] = h;
}

// ---------------------------------------------------------------------------
// Pure-fp16 MFMA GEMM, 2-phase double-buffered pipeline: C = A[M,K]*W[N,K]^T.
// 64x128 tile, BK=64, 4 waves 2x2.  STAGE(next) issued before compute(cur);
// single __syncthreads() per iter doubles as the vmcnt(0) drain.
// qkvz: 16x48 = 768 blocks = 3/CU balanced (best-measured 46.8us, replicated
// R2/R5).  R8's 128² tile regressed to 50.4us: M=1024 caps that grid at 384
// = 1.08 resident blocks/CU time-weighted (Occupancy 13.5%) -> the vmcnt(0)
// drain has no co-resident block to hide it.  768 @ 3/CU wins.
// ---------------------------------------------------------------------------
template <typename OutT>
__global__ __launch_bounds__(256, 2) void gemm_h16(const _Float16* __restrict__ A,
                                                   const _Float16* __restrict__ W,
                                                   OutT* __restrict__ C,
                                                   int MB, int NB, int K) {
    const int N = NB * 128;
    const int l = blockIdx.x;
    const int x = l & 7;
    const int tt = l >> 3;
    const int mb = tt % MB;
    const int nb = x + 8 * (tt / MB);
    const int m0 = mb * 64, n0 = nb * 128;

    const int t = threadIdx.x;
    const int wave = t >> 6;
    const int lane = t & 63;
    const int wr = (wave >> 1) * 32;
    const int wc = (wave & 1) * 64;
    const int l15 = lane & 15;
    const int quad = lane >> 4;
    const int srow = lane >> 3;
    const int slot = lane & 7;

    __shared__ __align__(16) _Float16 Ah[2][4096];
    __shared__ __align__(16) _Float16 Bh[2][8192];

    floatx4 acc[2][4];
#pragma unroll
    for (int i = 0; i < 2; ++i)
#pragma unroll
        for (int j = 0; j < 4; ++j) acc[i][j] = 0;

    auto stage = [&](int buf, int k0) {
#pragma unroll
        for (int g = 0; g < 2; ++g) {
            const int r = wave * 16 + g * 8 + srow;
            const int kc = slot ^ (r & 7);
            gl_lds16(A + (size_t)(m0 + r) * K + k0 + kc * 8,
                     &Ah[buf][(wave * 128 + g * 64) * 8]);
        }
#pragma unroll
        for (int g = 0; g < 4; ++g) {
            const int r = wave * 32 + g * 8 + srow;
            const int kc = slot ^ (r & 7);
            gl_lds16(W + (size_t)(n0 + r) * K + k0 + kc * 8,
                     &Bh[buf][(wave * 256 + g * 64) * 8]);
        }
    };

    const int NIT = K >> 6;
    stage(0, 0);
    __syncthreads();
    int cur = 0;
    for (int it = 0; it < NIT; ++it) {
        if (it + 1 < NIT) stage(cur ^ 1, (it + 1) * 64);
        half8 af[2][2], bf[4][2];
#pragma unroll
        for (int mt = 0; mt < 2; ++mt)
#pragma unroll
            for (int ks = 0; ks < 2; ++ks) {
                const int m = wr + mt * 16 + l15;
                const int kq = ks * 4 + quad;
                af[mt][ks] = *(const half8*)&Ah[cur][(m * 8 + (kq ^ (m & 7))) * 8];
            }
#pragma unroll
        for (int nt = 0; nt < 4; ++nt)
#pragma unroll
            for (int ks = 0; ks < 2; ++ks) {
                const int n = wc + nt * 16 + l15;
                const int kq = ks * 4 + quad;
                bf[nt][ks] = *(const half8*)&Bh[cur][(n * 8 + (kq ^ (n & 7))) * 8];
            }
#pragma unroll
        for (int mt = 0; mt < 2; ++mt)
#pragma unroll
            for (int nt = 0; nt < 4; ++nt)
#pragma unroll
                for (int ks = 0; ks < 2; ++ks)
                    acc[mt][nt] = __builtin_amdgcn_mfma_f32_16x16x32_f16(
                        af[mt][ks], bf[nt][ks], acc[mt][nt], 0, 0, 0);
        if (it + 1 < NIT) {
            __syncthreads();
            cur ^= 1;
        }
    }
#pragma unroll
    for (int mt = 0; mt < 2; ++mt)
#pragma unroll
        for (int nt = 0; nt < 4; ++nt) {
            const int c = n0 + wc + nt * 16 + l15;
#pragma unroll
            for (int reg = 0; reg < 4; ++reg) {
                const int r = m0 + wr + mt * 16 + quad * 4 + reg;
                C[(size_t)r * N + c] = (OutT)acc[mt][nt][reg];
            }
        }
}

// ---------------------------------------------------------------------------
// ba projection fused with gates.  1024 blocks.  (R3 version, no fusion.)
// ---------------------------------------------------------------------------
__global__ __launch_bounds__(256) void gemm_ba_gates(const float* __restrict__ A,
                                                     const float* __restrict__ W,
                                                     const float* __restrict__ dt_bias,
                                                     const float* __restrict__ A_log,
                                                     float* __restrict__ lgd,
                                                     float* __restrict__ bet) {
    const int m = blockIdx.x;
    const int tid = threadIdx.x;
    const int kl = tid & 31;
    const int ng = tid >> 5;
    const float* Arow = A + (size_t)m * 2048;
    __shared__ float sba[32];

    float4 a4[16];
#pragma unroll
    for (int j = 0; j < 16; ++j)
        a4[j] = *(const float4*)(Arow + j * 128 + kl * 4);

#pragma unroll
    for (int nn = 0; nn < 4; ++nn) {
        const int n = nn * 8 + ng;
        const float* Wrow = W + (size_t)n * 2048;
        float acc = 0.f;
#pragma unroll
        for (int j = 0; j < 16; ++j) {
            const float4 w4 = *(const float4*)(Wrow + j * 128 + kl * 4);
            acc = fmaf(a4[j].x, w4.x, acc);
            acc = fmaf(a4[j].y, w4.y, acc);
            acc = fmaf(a4[j].z, w4.z, acc);
            acc = fmaf(a4[j].w, w4.w, acc);
        }
        acc += __shfl_xor(acc, 1, 64);
        acc += __shfl_xor(acc, 2, 64);
        acc += __shfl_xor(acc, 4, 64);
        acc += __shfl_xor(acc, 8, 64);
        acc += __shfl_xor(acc, 16, 64);
        if (kl == 0) sba[n] = acc;
    }
    __syncthreads();
    if (tid < 16) {
        const int vh = tid, kh = vh >> 1, r = vh & 1;
        const float b = sba[kh * 4 + r];
        const float a = sba[kh * 4 + 2 + r];
        bet[m * 16 + vh] = 1.f / (1.f + expf(-b));
        const float xx = a + dt_bias[vh];
        const float sp = (xx > 0.f) ? (xx + log1pf(expf(-xx))) : log1pf(expf(xx));
        lgd[m * 16 + vh] = -expf(A_log[vh]) * sp;
    }
}

// ---------------------------------------------------------------------------
// Depthwise causal conv1d (K=4) + SiLU + fused q/k L2-norm.
// ---------------------------------------------------------------------------
__global__ __launch_bounds__(512) void conv_silu_l2(const _Float16* __restrict__ qkvz,
                                                    const float* __restrict__ conv_w,
                                                    _Float16* __restrict__ qc,
                                                    _Float16* __restrict__ kc,
                                                    _Float16* __restrict__ vc) {
    const int t = blockIdx.x;
    const int c = threadIdx.x * 8;
    int col;
    _Float16* dst;
    bool isqk;
    float extra = 1.f;
    if (c < 1024) {
        col = ((c >> 7) * 768) + (c & 127);
        dst = qc + t * 1024 + c;
        isqk = true;
        extra = 0.08838834764831845f;
    } else if (c < 2048) {
        const int cc = c - 1024;
        col = ((cc >> 7) * 768) + 128 + (cc & 127);
        dst = kc + t * 1024 + cc;
        isqk = true;
    } else {
        const int cc = c - 2048;
        col = ((cc >> 8) * 768) + 256 + (cc & 255);
        dst = vc + (size_t)t * 2048 + cc;
        isqk = false;
    }
    const size_t gb = (size_t)t * QKVZ_N + col;
    const half8 x3 = *(const half8*)(qkvz + gb);
    half8 x2, x1, x0;
    if (t >= 1) x2 = *(const half8*)(qkvz + gb - QKVZ_N);
    if (t >= 2) x1 = *(const half8*)(qkvz + gb - 2 * (size_t)QKVZ_N);
    if (t >= 3) x0 = *(const half8*)(qkvz + gb - 3 * (size_t)QKVZ_N);

    float y[8];
    float ss = 0.f;
#pragma unroll
    for (int u = 0; u < 8; ++u) {
        const float4 wv = *(const float4*)(conv_w + (c + u) * 4);
        float acc = (float)x3[u] * wv.w;
        if (t >= 1) acc = fmaf((float)x2[u], wv.z, acc);
        if (t >= 2) acc = fmaf((float)x1[u], wv.y, acc);
        if (t >= 3) acc = fmaf((float)x0[u], wv.x, acc);
        acc = acc * (1.f / (1.f + expf(-acc)));   // silu
        y[u] = acc;
        ss = fmaf(acc, acc, ss);
    }
    half8 ov;
    if (isqk) {
        ss += __shfl_xor(ss, 1, 64);
        ss += __shfl_xor(ss, 2, 64);
        ss += __shfl_xor(ss, 4, 64);
        ss += __shfl_xor(ss, 8, 64);
        const float r = rsqrtf(ss + 1e-6f) * extra;
#pragma unroll
        for (int u = 0; u < 8; ++u) ov[u] = (_Float16)(y[u] * r);
    } else {
#pragma unroll
        for (int u = 0; u < 8; ++u) ov[u] = (_Float16)y[u];
    }
    *(half8*)dst = ov;
}

// ---------------------------------------------------------------------------
// chunk_prep: per (chunk c, v-head h), fully parallel (256 blocks).
// __launch_bounds__(256, 1): the only change vs R3.  float x[64] must stay
// in registers (rules #19/#20: R4's compile demoted it to scratch at the
// default occupancy target -> 89us; the pin removes that failure mode; the
// kernel runs 1 block/CU anyway so the cap is free).
// ---------------------------------------------------------------------------
__global__ __launch_bounds__(256, 1) void chunk_prep(
    const _Float16* __restrict__ qch, const _Float16* __restrict__ kch,
    const _Float16* __restrict__ vch, const float* __restrict__ lgd,
    const float* __restrict__ bet, _Float16* __restrict__ CH,
    float* __restrict__ gamC) {
    const int blk = blockIdx.x;
    const int c = blk >> 4, h = blk & 15, kh = h >> 1;
    const int c0 = c * 64;
    const int tid = threadIdx.x, lane = tid & 63, wave = tid >> 6;
    const int l15 = lane & 15, quad = lane >> 4;

    __shared__ __align__(16) _Float16 Ksh[8192];
    __shared__ __align__(16) _Float16 Qsh[8192];
    __shared__ float Amat[64 * 65];
    __shared__ float Gs[64], Bets[64], Gam[64];

    {
        const int t = tid >> 2, kc0 = (tid & 3) * 4;
        const size_t gb = (size_t)(c0 + t) * 1024 + kh * 128;
#pragma unroll
        for (int i = 0; i < 4; ++i) {
            const int kc = kc0 + i;
            half8 kv = *(const half8*)(kch + gb + kc * 8);
            half8 qv = *(const half8*)(qch + gb + kc * 8);
            const int chl = t * 16 + (kc ^ (t & 15));
            *(half8*)&Ksh[chl * 8] = kv;
            *(half8*)&Qsh[chl * 8] = qv;
        }
    }
    if (tid < 64) {
        float g = lgd[(size_t)(c0 + tid) * 16 + h];
#pragma unroll
        for (int off = 1; off < 64; off <<= 1) {
            float y = __shfl_up(g, off, 64);
            if (tid >= off) g += y;
        }
        Gs[tid] = g;
        Gam[tid] = expf(g);
        Bets[tid] = bet[(size_t)(c0 + tid) * 16 + h];
    }
    __syncthreads();

    _Float16* CHb = CH + (size_t)(c * 16 + h) * 36864;
    _Float16* Ug = CHb;
    _Float16* Wtg = CHb + 8192;
    _Float16* Khg = CHb + 16384;
    _Float16* Qgg = CHb + 24576;
    _Float16* Lg = CHb + 32768;

    {
        floatx4 accKK[4], accQK[4];
#pragma unroll
        for (int tt = 0; tt < 4; ++tt) { accKK[tt] = 0; accQK[tt] = 0; }
        half8 bfK[4];
#pragma unroll
        for (int ks = 0; ks < 4; ++ks) {
            const int i = wave * 16 + l15;
            const int kc = ks * 4 + quad;
            bfK[ks] = *(const half8*)&Ksh[(i * 16 + (kc ^ (i & 15))) * 8];
        }
#pragma unroll
        for (int tt = 0; tt < 4; ++tt) {
            const int t = tt * 16 + l15;
#pragma unroll
            for (int ks = 0; ks < 4; ++ks) {
                const int kc = ks * 4 + quad;
                const int chl = (t * 16 + (kc ^ (t & 15))) * 8;
                half8 afK = *(const half8*)&Ksh[chl];
                half8 afQ = *(const half8*)&Qsh[chl];
                accKK[tt] = __builtin_amdgcn_mfma_f32_16x16x32_f16(afK, bfK[ks], accKK[tt], 0, 0, 0);
                accQK[tt] = __builtin_amdgcn_mfma_f32_16x16x32_f16(afQ, bfK[ks], accQK[tt], 0, 0, 0);
            }
        }
        const int ii = wave * 16 + l15;
        const float Gi = Gs[ii];
#pragma unroll
        for (int tt = 0; tt < 4; ++tt)
#pragma unroll
            for (int r = 0; r < 4; ++r) {
                const int t = tt * 16 + quad * 4 + r;
                const float Gt = Gs[t];
                const float ratio = (ii <= t) ? expf(Gt - Gi) : 0.f;
                if (ii < t) Amat[t * 65 + ii] = Bets[t] * ratio * accKK[tt][r];
                Lg[t * 64 + ii] = (_Float16)((ii <= t) ? ratio * accQK[tt][r] : 0.f);
            }
    }
    __syncthreads();

    {
        const int j = tid;
        float x[64];
        if (j < 128) {
#pragma unroll
            for (int t = 0; t < 64; ++t)
                x[t] = Bets[t] * (float)vch[(size_t)(c0 + t) * 2048 + h * 128 + j];
        } else {
            const int k = j - 128;
#pragma unroll
            for (int t = 0; t < 64; ++t) {
                const int chl = t * 16 + ((k >> 3) ^ (t & 15));
                x[t] = Bets[t] * Gam[t] * (float)Ksh[chl * 8 + (k & 7)];
            }
        }
#pragma unroll
        for (int t = 1; t < 64; ++t) {
            float acc = 0.f;
#pragma unroll
            for (int i = 0; i < t; ++i) acc = fmaf(Amat[t * 65 + i], x[i], acc);
            x[t] -= acc;
        }
        if (j < 128) {
#pragma unroll
            for (int t = 0; t < 64; t += 4) {
                half4 w4;
                w4[0] = (_Float16)x[t]; w4[1] = (_Float16)x[t + 1];
                w4[2] = (_Float16)x[t + 2]; w4[3] = (_Float16)x[t + 3];
                *(half4*)&Wtg[j * 64 + t] = w4;
            }
        } else {
            const int k = j - 128;
#pragma unroll
            for (int t = 0; t < 64; ++t) Ug[t * 128 + k] = (_Float16)x[t];
        }
    }

    {
        const float g63 = Gs[63];
        const int k = tid >> 1, cb = (tid & 1) * 32;
#pragma unroll
        for (int cc = 0; cc < 32; cc += 4) {
            half4 o4;
#pragma unroll
            for (int u = 0; u < 4; ++u) {
                const int ci = cb + cc + u;
                const int chl = ci * 16 + ((k >> 3) ^ (ci & 15));
                o4[u] = (_Float16)(expf(g63 - Gs[ci]) * (float)Ksh[chl * 8 + (k & 7)]);
            }
            *(half4*)&Khg[k * 64 + cb + cc] = o4;
        }
        const int cq = tid >> 2, kb = (tid & 3) * 4;
        const float gam = Gam[cq];
#pragma unroll
        for (int kc = 0; kc < 4; ++kc) {
            const int kcc = kb + kc;
            half8 q8 = *(const half8*)&Qsh[(cq * 16 + (kcc ^ (cq & 15))) * 8];
            half8 s8;
#pragma unroll
            for (int u = 0; u < 8; ++u) s8[u] = (_Float16)(gam * (float)q8[u]);
            *(half8*)&Qgg[cq * 128 + kcc * 8] = s8;
        }
        if (tid == 0) gamC[c * 16 + h] = Gam[63];
    }
}

// ---------------------------------------------------------------------------
// chunk_scan: 128 blocks (16 heads x 8 v-slices of 16), 256 threads.
// Waves split work; operands double-buffered global->VGPR; S^T/Dt in LDS.
// ---------------------------------------------------------------------------
struct ScanOps {
    half8 aU[4];
    half8 aQ[4];
    half8 aL[2];
    half8 aK[2][2];
    half4 wv;
    float gC;
};

__global__ __launch_bounds__(256) void chunk_scan(const _Float16* __restrict__ CH,
                                                  const float* __restrict__ gamC,
                                                  float* __restrict__ o) {
    const int h = blockIdx.x & 15;
    const int vsl = blockIdx.x >> 4;
    const int tid = threadIdx.x, lane = tid & 63, wave = tid >> 6;
    const int l15 = lane & 15, quad = lane >> 4;
    const int tw = wave * 16;
    const int kw = wave * 32;
    const int sKey = l15 << 1;
    const int dKey = (l15 << 1) & 14;

    __shared__ __align__(16) _Float16 Ssh[16 * 128];
    __shared__ __align__(16) _Float16 Dsh[16 * 64];

    *(half8*)&Ssh[tid * 8] = half8{0, 0, 0, 0, 0, 0, 0, 0};
    floatx4 Sacc[2];
    Sacc[0] = 0; Sacc[1] = 0;
    __syncthreads();

    auto loadOps = [&](ScanOps& S, int c) {
        const _Float16* CHb = CH + (size_t)(c * 16 + h) * 36864;
#pragma unroll
        for (int ks = 0; ks < 4; ++ks) {
            S.aU[ks] = *(const half8*)(CHb + (tw + l15) * 128 + ks * 32 + quad * 8);
            S.aQ[ks] = *(const half8*)(CHb + 24576 + (tw + l15) * 128 + ks * 32 + quad * 8);
        }
#pragma unroll
        for (int cs = 0; cs < 2; ++cs) {
            S.aL[cs] = *(const half8*)(CHb + 32768 + (tw + l15) * 64 + cs * 32 + quad * 8);
#pragma unroll
            for (int kt = 0; kt < 2; ++kt)
                S.aK[kt][cs] = *(const half8*)(CHb + 16384 + (kw + kt * 16 + l15) * 64 + cs * 32 + quad * 8);
        }
        S.wv = *(const half4*)(CHb + 8192 + (vsl * 16 + l15) * 64 + tw + quad * 4);
        S.gC = gamC[c * 16 + h];
    };

    auto chunkBody = [&](const ScanOps& S, int c) {
        half8 bs[4];
#pragma unroll
        for (int ks = 0; ks < 4; ++ks)
            bs[ks] = *(const half8*)&Ssh[(l15 * 32 + ((ks * 8 + quad * 2) ^ sKey)) * 4];
        floatx4 xa = {0.f, 0.f, 0.f, 0.f};
#pragma unroll
        for (int ks = 0; ks < 4; ++ks)
            xa = __builtin_amdgcn_mfma_f32_16x16x32_f16(S.aU[ks], bs[ks], xa, 0, 0, 0);
        half4 d4;
#pragma unroll
        for (int r = 0; r < 4; ++r) d4[r] = (_Float16)((float)S.wv[r] - xa[r]);
        *(half4*)&Dsh[(l15 * 16 + ((wave * 4 + quad) ^ dKey)) * 4] = d4;
        __syncthreads();

        half8 bd[2];
#pragma unroll
        for (int cs = 0; cs < 2; ++cs)
            bd[cs] = *(const half8*)&Dsh[(l15 * 16 + ((cs * 8 + quad * 2) ^ dKey)) * 4];
        floatx4 oacc = {0.f, 0.f, 0.f, 0.f};
#pragma unroll
        for (int ks = 0; ks < 4; ++ks)
            oacc = __builtin_amdgcn_mfma_f32_16x16x32_f16(S.aQ[ks], bs[ks], oacc, 0, 0, 0);
#pragma unroll
        for (int cs = 0; cs < 2; ++cs)
            oacc = __builtin_amdgcn_mfma_f32_16x16x32_f16(S.aL[cs], bd[cs], oacc, 0, 0, 0);
#pragma unroll
        for (int kt = 0; kt < 2; ++kt) {
#pragma unroll
            for (int r = 0; r < 4; ++r) Sacc[kt][r] *= S.gC;
#pragma unroll
            for (int cs = 0; cs < 2; ++cs)
                Sacc[kt] = __builtin_amdgcn_mfma_f32_16x16x32_f16(S.aK[kt][cs], bd[cs], Sacc[kt], 0, 0, 0);
        }
        const int col = h * 128 + vsl * 16 + l15;
#pragma unroll
        for (int r = 0; r < 4; ++r)
            o[(size_t)(c * 64 + tw + quad * 4 + r) * 2048 + col] = oacc[r];
#pragma unroll
        for (int kt = 0; kt < 2; ++kt) {
            half4 s4;
#pragma unroll
            for (int r = 0; r < 4; ++r) s4[r] = (_Float16)Sacc[kt][r];
            *(half4*)&Ssh[(l15 * 32 + ((wave * 8 + kt * 4 + quad) ^ sKey)) * 4] = s4;
        }
        __syncthreads();
    };

    ScanOps A_, B_;
    loadOps(A_, 0);
#pragma unroll 1
    for (int cc = 0; cc < 16; cc += 2) {
        loadOps(B_, cc + 1);
        chunkBody(A_, cc);
        if (cc + 2 < 16) loadOps(A_, cc + 2);
        chunkBody(B_, cc + 1);
    }
}

// ---------------------------------------------------------------------------
// Gated RMSNorm: xf = o * silu(z); xn = xf * rsqrt(mean(xf^2)+eps) * w
// ---------------------------------------------------------------------------
__global__ __launch_bounds__(64) void gated_norm(const float* __restrict__ o,
                                                 const _Float16* __restrict__ qkvz,
                                                 const float* __restrict__ nw,
                                                 _Float16* __restrict__ xn) {
    const int b = blockIdx.x;
    const int t = b >> 4;
    const int vh = b & 15;
    const int kh = vh >> 1;
    const int r = vh & 1;
    const float* op = o + (size_t)t * 2048 + vh * 128;
    const _Float16* zp = qkvz + (size_t)t * QKVZ_N + kh * 768 + 512 + r * 128;
    const int j = threadIdx.x * 2;
    const float2 ov = *(const float2*)(op + j);
    const half2t zv = *(const half2t*)(zp + j);
    const float z0 = (float)zv[0], z1 = (float)zv[1];
    const float f0 = ov.x * z0 / (1.f + expf(-z0));
    const float f1 = ov.y * z1 / (1.f + expf(-z1));
    float ss = f0 * f0 + f1 * f1;
#pragma unroll
    for (int m = 1; m < 64; m <<= 1) ss += __shfl_xor(ss, m, 64);
    const float rs = rsqrtf(ss * (1.f / 128.f) + 1e-6f);
    _Float16* xp = xn + (size_t)t * 2048 + vh * 128;
    half2t y;
    y[0] = (_Float16)(f0 * rs * nw[j]);
    y[1] = (_Float16)(f1 * rs * nw[j + 1]);
    *(half2t*)(xp + j) = y;
}

// ---------------------------------------------------------------------------
extern "C" void kernel_launch(void* const* d_in, const int* in_sizes, int n_in,
                              void* d_out, int out_size, void* d_ws, size_t ws_size,
                              hipStream_t stream) {
    const float* hidden  = (const float*)d_in[0];
    const float* w_qkvz  = (const float*)d_in[1];
    const float* w_ba    = (const float*)d_in[2];
    const float* conv_w  = (const float*)d_in[3];
    const float* dt_bias = (const float*)d_in[4];
    const float* A_log   = (const float*)d_in[5];
    const float* norm_w  = (const float*)d_in[6];
    const float* w_out   = (const float*)d_in[7];
    float* out = (float*)d_out;

    // workspace layout (~63.2 MB), lifetime-based overlaps:
    //   hidden_h overlaps o        (hidden_h dead after qkvz GEMM)
    //   CH + xn_h overlap wqkvz_h  (wqkvz_h dead after qkvz GEMM)
    char* w = (char*)d_ws;
    _Float16*  qkvz_h = (_Float16*)(w);                 // 12,582,912 B (fp16)
    _Float16*  qch    = (_Float16*)(w + 12713984);      //  2,097,152 B
    _Float16*  kch    = (_Float16*)(w + 14811136);      //  2,097,152 B
    _Float16*  vch    = (_Float16*)(w + 16908288);      //  4,194,304 B
    float*     lgd    = (float*)(w + 21102592);         //     65,536 B
    float*     bet    = (float*)(w + 21168128);         //     65,536 B
    float*     gamC   = (float*)(w + 21233664);         //      4,096 B
    float*     o      = (float*)(w + 21237760);         //  8,388,608 B
    _Float16*  hid_h  = (_Float16*)(w + 21237760);      //  overlaps o
    _Float16*  wqk_h  = (_Float16*)(w + 29626368);      // 25,165,824 B
    _Float16*  CH     = (_Float16*)(w + 29626368);      //  overlaps wqk_h
    _Float16*  xn_h   = (_Float16*)(w + 29626368 + 18874368);  // after CH
    _Float16*  wout_h = (_Float16*)(w + 54792192);      //  8,388,608 B

    const int n0 = HIDDEN * T_LEN / 4;       //  524,288 float4s
    const int n1 = QKVZ_N * HIDDEN / 4;      // 3,145,728
    const int n2 = VAL_DIM * HIDDEN / 4;     // 1,048,576
    cvt3<<<(n0 + n1 + n2 + 255) / 256, 256, 0, stream>>>(hidden, hid_h, n0,
                                                         w_qkvz, wqk_h, n1,
                                                         w_out, wout_h, n2);

    gemm_h16<_Float16><<<16 * 48, 256, 0, stream>>>(hid_h, wqk_h, qkvz_h, 16, 48, HIDDEN);
    gemm_ba_gates<<<T_LEN, 256, 0, stream>>>(hidden, w_ba, dt_bias, A_log, lgd, bet);
    conv_silu_l2<<<T_LEN, 512, 0, stream>>>(qkvz_h, conv_w, qch, kch, vch);
    chunk_prep<<<256, 256, 0, stream>>>(qch, kch, vch, lgd, bet, CH, gamC);
    chunk_scan<<<128, 256, 0, stream>>>(CH, gamC, o);
    gated_norm<<<T_LEN * 16, 64, 0, stream>>>(o, qkvz_h, norm_w, xn_h);
    gemm_h16<float><<<16 * 16, 256, 0, stream>>>(xn_h, wout_h, out, 16, 16, HIDDEN);
}

// Round 11
// 277.019 us; speedup vs baseline: 1.1737x; 1.0411x over previous
//
#include <hip/hip_runtime.h>
#include <math.h>

// ---------------- problem constants ----------------
#define T_LEN   1024
#define HIDDEN  2048
#define QKVZ_N  6144   // 2*KEY_DIM + 2*VALUE_DIM
#define VAL_DIM 2048

typedef _Float16 half8 __attribute__((ext_vector_type(8)));
typedef _Float16 half4 __attribute__((ext_vector_type(4)));
typedef _Float16 half2t __attribute__((ext_vector_type(2)));
typedef float floatx4 __attribute__((ext_vector_type(4)));

__device__ __forceinline__ float sigmoidf_(float x) { return 1.f / (1.f + expf(-x)); }

// async global->LDS, 16B per lane; LDS dest = wave-uniform base + lane*16
__device__ __forceinline__ void gl_lds16(const _Float16* g, _Float16* l) {
    __builtin_amdgcn_global_load_lds(
        (const __attribute__((address_space(1))) void*)g,
        (__attribute__((address_space(3))) void*)l, 16, 0, 0);
}

// ---------------------------------------------------------------------------
// fused fp32 -> fp16 bulk convert of the three GEMM operands (1 launch)
// ---------------------------------------------------------------------------
__global__ __launch_bounds__(256) void cvt3(const float* __restrict__ s0, _Float16* __restrict__ d0, int n0,
                                            const float* __restrict__ s1, _Float16* __restrict__ d1, int n1,
                                            const float* __restrict__ s2, _Float16* __restrict__ d2, int n2) {
    int i = blockIdx.x * 256 + threadIdx.x;
    const float* s;
    _Float16* d;
    if (i < n0) { s = s0; d = d0; }
    else if (i < n0 + n1) { s = s1; d = d1; i -= n0; }
    else if (i < n0 + n1 + n2) { s = s2; d = d2; i -= n0 + n1; }
    else return;
    const float4 v = ((const float4*)s)[i];
    half4 h;
    h[0] = (_Float16)v.x; h[1] = (_Float16)v.y;
    h[2] = (_Float16)v.z; h[3] = (_Float16)v.w;
    *(half4*)&d[i * 4] = h;
}

// ---------------------------------------------------------------------------
// Pure-fp16 MFMA GEMM, 2-phase double-buffered pipeline: C = A[M,K]*W[N,K]^T.
// 64 x (NT*32) tile, BK=64, 4 waves 2x2.  STAGE(next) issued before
// compute(cur); single __syncthreads() per iter doubles as the vmcnt(0)
// drain.  NT=4 instantiation is bit-identical to the R9 qkvz kernel
// (best-measured <40.2us).
//   qkvz (NT=4, 64x128): grid 16x48 = 768 = 3/CU balanced.
//   out  (NT=2, 64x64):  grid 16x32 = 512 = 2/CU balanced -- was 256 =
//     1/CU, where the per-iter vmcnt(0) drain had no co-resident block to
//     hide it (the R8-measured failure mode).  LDS 2x(8+8)KB = 32KB.
// Swizzle: row r stores chunk kq at slot kq^(r&7) (involution, both sides).
// ---------------------------------------------------------------------------
template <int NT, typename OutT>
__global__ __launch_bounds__(256, 2) void gemm_h16(const _Float16* __restrict__ A,
                                                   const _Float16* __restrict__ W,
                                                   OutT* __restrict__ C,
                                                   int MB, int NB, int K) {
    const int BN = NT * 32;
    const int N = NB * BN;
    const int l = blockIdx.x;
    const int x = l & 7;
    const int tt = l >> 3;
    const int mb = tt % MB;
    const int nb = x + 8 * (tt / MB);
    const int m0 = mb * 64, n0 = nb * BN;

    const int t = threadIdx.x;
    const int wave = t >> 6;
    const int lane = t & 63;
    const int wr = (wave >> 1) * 32;
    const int wc = (wave & 1) * (BN / 2);
    const int l15 = lane & 15;
    const int quad = lane >> 4;
    const int srow = lane >> 3;
    const int slot = lane & 7;

    __shared__ __align__(16) _Float16 Ah[2][4096];      //  64 rows x 64 k
    __shared__ __align__(16) _Float16 Bh[2][BN * 64];   //  BN rows x 64 k

    floatx4 acc[2][NT];
#pragma unroll
    for (int i = 0; i < 2; ++i)
#pragma unroll
        for (int j = 0; j < NT; ++j) acc[i][j] = 0;

    auto stage = [&](int buf, int k0) {
#pragma unroll
        for (int g = 0; g < 2; ++g) {                   // A: 16 rows/wave
            const int r = wave * 16 + g * 8 + srow;
            const int kc = slot ^ (r & 7);
            gl_lds16(A + (size_t)(m0 + r) * K + k0 + kc * 8,
                     &Ah[buf][(wave * 128 + g * 64) * 8]);
        }
#pragma unroll
        for (int g = 0; g < NT; ++g) {                  // B: NT*8 rows/wave
            const int r = wave * (NT * 8) + g * 8 + srow;
            const int kc = slot ^ (r & 7);
            gl_lds16(W + (size_t)(n0 + r) * K + k0 + kc * 8,
                     &Bh[buf][(wave * (NT * 64) + g * 64) * 8]);
        }
    };

    const int NIT = K >> 6;
    stage(0, 0);
    __syncthreads();
    int cur = 0;
    for (int it = 0; it < NIT; ++it) {
        if (it + 1 < NIT) stage(cur ^ 1, (it + 1) * 64);
        half8 af[2][2], bf[NT][2];
#pragma unroll
        for (int mt = 0; mt < 2; ++mt)
#pragma unroll
            for (int ks = 0; ks < 2; ++ks) {
                const int m = wr + mt * 16 + l15;
                const int kq = ks * 4 + quad;
                af[mt][ks] = *(const half8*)&Ah[cur][(m * 8 + (kq ^ (m & 7))) * 8];
            }
#pragma unroll
        for (int nt = 0; nt < NT; ++nt)
#pragma unroll
            for (int ks = 0; ks < 2; ++ks) {
                const int n = wc + nt * 16 + l15;
                const int kq = ks * 4 + quad;
                bf[nt][ks] = *(const half8*)&Bh[cur][(n * 8 + (kq ^ (n & 7))) * 8];
            }
#pragma unroll
        for (int mt = 0; mt < 2; ++mt)
#pragma unroll
            for (int nt = 0; nt < NT; ++nt)
#pragma unroll
                for (int ks = 0; ks < 2; ++ks)
                    acc[mt][nt] = __builtin_amdgcn_mfma_f32_16x16x32_f16(
                        af[mt][ks], bf[nt][ks], acc[mt][nt], 0, 0, 0);
        if (it + 1 < NIT) {
            __syncthreads();
            cur ^= 1;
        }
    }
#pragma unroll
    for (int mt = 0; mt < 2; ++mt)
#pragma unroll
        for (int nt = 0; nt < NT; ++nt) {
            const int c = n0 + wc + nt * 16 + l15;
#pragma unroll
            for (int reg = 0; reg < 4; ++reg) {
                const int r = m0 + wr + mt * 16 + quad * 4 + reg;
                C[(size_t)r * N + c] = (OutT)acc[mt][nt][reg];
            }
        }
}

// ---------------------------------------------------------------------------
// ba projection fused with gates.  1024 blocks.
// ---------------------------------------------------------------------------
__global__ __launch_bounds__(256) void gemm_ba_gates(const float* __restrict__ A,
                                                     const float* __restrict__ W,
                                                     const float* __restrict__ dt_bias,
                                                     const float* __restrict__ A_log,
                                                     float* __restrict__ lgd,
                                                     float* __restrict__ bet) {
    const int m = blockIdx.x;
    const int tid = threadIdx.x;
    const int kl = tid & 31;
    const int ng = tid >> 5;
    const float* Arow = A + (size_t)m * 2048;
    __shared__ float sba[32];

    float4 a4[16];
#pragma unroll
    for (int j = 0; j < 16; ++j)
        a4[j] = *(const float4*)(Arow + j * 128 + kl * 4);

#pragma unroll
    for (int nn = 0; nn < 4; ++nn) {
        const int n = nn * 8 + ng;
        const float* Wrow = W + (size_t)n * 2048;
        float acc = 0.f;
#pragma unroll
        for (int j = 0; j < 16; ++j) {
            const float4 w4 = *(const float4*)(Wrow + j * 128 + kl * 4);
            acc = fmaf(a4[j].x, w4.x, acc);
            acc = fmaf(a4[j].y, w4.y, acc);
            acc = fmaf(a4[j].z, w4.z, acc);
            acc = fmaf(a4[j].w, w4.w, acc);
        }
        acc += __shfl_xor(acc, 1, 64);
        acc += __shfl_xor(acc, 2, 64);
        acc += __shfl_xor(acc, 4, 64);
        acc += __shfl_xor(acc, 8, 64);
        acc += __shfl_xor(acc, 16, 64);
        if (kl == 0) sba[n] = acc;
    }
    __syncthreads();
    if (tid < 16) {
        const int vh = tid, kh = vh >> 1, r = vh & 1;
        const float b = sba[kh * 4 + r];
        const float a = sba[kh * 4 + 2 + r];
        bet[m * 16 + vh] = 1.f / (1.f + expf(-b));
        const float xx = a + dt_bias[vh];
        const float sp = (xx > 0.f) ? (xx + log1pf(expf(-xx))) : log1pf(expf(xx));
        lgd[m * 16 + vh] = -expf(A_log[vh]) * sp;
    }
}

// ---------------------------------------------------------------------------
// Depthwise causal conv1d (K=4) + SiLU + fused q/k L2-norm.
// ---------------------------------------------------------------------------
__global__ __launch_bounds__(512) void conv_silu_l2(const _Float16* __restrict__ qkvz,
                                                    const float* __restrict__ conv_w,
                                                    _Float16* __restrict__ qc,
                                                    _Float16* __restrict__ kc,
                                                    _Float16* __restrict__ vc) {
    const int t = blockIdx.x;
    const int c = threadIdx.x * 8;
    int col;
    _Float16* dst;
    bool isqk;
    float extra = 1.f;
    if (c < 1024) {
        col = ((c >> 7) * 768) + (c & 127);
        dst = qc + t * 1024 + c;
        isqk = true;
        extra = 0.08838834764831845f;
    } else if (c < 2048) {
        const int cc = c - 1024;
        col = ((cc >> 7) * 768) + 128 + (cc & 127);
        dst = kc + t * 1024 + cc;
        isqk = true;
    } else {
        const int cc = c - 2048;
        col = ((cc >> 8) * 768) + 256 + (cc & 255);
        dst = vc + (size_t)t * 2048 + cc;
        isqk = false;
    }
    const size_t gb = (size_t)t * QKVZ_N + col;
    const half8 x3 = *(const half8*)(qkvz + gb);
    half8 x2, x1, x0;
    if (t >= 1) x2 = *(const half8*)(qkvz + gb - QKVZ_N);
    if (t >= 2) x1 = *(const half8*)(qkvz + gb - 2 * (size_t)QKVZ_N);
    if (t >= 3) x0 = *(const half8*)(qkvz + gb - 3 * (size_t)QKVZ_N);

    float y[8];
    float ss = 0.f;
#pragma unroll
    for (int u = 0; u < 8; ++u) {
        const float4 wv = *(const float4*)(conv_w + (c + u) * 4);
        float acc = (float)x3[u] * wv.w;
        if (t >= 1) acc = fmaf((float)x2[u], wv.z, acc);
        if (t >= 2) acc = fmaf((float)x1[u], wv.y, acc);
        if (t >= 3) acc = fmaf((float)x0[u], wv.x, acc);
        acc = acc * (1.f / (1.f + expf(-acc)));   // silu
        y[u] = acc;
        ss = fmaf(acc, acc, ss);
    }
    half8 ov;
    if (isqk) {
        ss += __shfl_xor(ss, 1, 64);
        ss += __shfl_xor(ss, 2, 64);
        ss += __shfl_xor(ss, 4, 64);
        ss += __shfl_xor(ss, 8, 64);
        const float r = rsqrtf(ss + 1e-6f) * extra;
#pragma unroll
        for (int u = 0; u < 8; ++u) ov[u] = (_Float16)(y[u] * r);
    } else {
#pragma unroll
        for (int u = 0; u < 8; ++u) ov[u] = (_Float16)y[u];
    }
    *(half8*)dst = ov;
}

// ---------------------------------------------------------------------------
// chunk_prep: per (chunk c, v-head h), fully parallel (256 blocks).
// __launch_bounds__(256, 1): float x[64] must stay in registers (rule #20).
// Solve: Amat rows padded to 68 floats (16B-aligned), upper triangle
// zero-initialized, forward substitution reads float4 rows with 4
// independent accumulators.  Per-thread LDS reads for the solve: 2016
// scalar ds_read_b32 -> ~528 ds_read_b128, dependent chain 4x shorter.
// Extra tail terms multiply zeroed A entries -> contribute exactly 0.
// ---------------------------------------------------------------------------
__global__ __launch_bounds__(256, 1) void chunk_prep(
    const _Float16* __restrict__ qch, const _Float16* __restrict__ kch,
    const _Float16* __restrict__ vch, const float* __restrict__ lgd,
    const float* __restrict__ bet, _Float16* __restrict__ CH,
    float* __restrict__ gamC) {
    const int blk = blockIdx.x;
    const int c = blk >> 4, h = blk & 15, kh = h >> 1;
    const int c0 = c * 64;
    const int tid = threadIdx.x, lane = tid & 63, wave = tid >> 6;
    const int l15 = lane & 15, quad = lane >> 4;

    __shared__ __align__(16) _Float16 Ksh[8192];
    __shared__ __align__(16) _Float16 Qsh[8192];
    __shared__ __align__(16) float Amat[64 * 68];
    __shared__ float Gs[64], Bets[64], Gam[64];

    // zero Amat (upper triangle + pad must be 0 for the float4 solve)
#pragma unroll
    for (int i = 0; i < 17; ++i) Amat[tid + i * 256] = 0.f;

    {
        const int t = tid >> 2, kc0 = (tid & 3) * 4;
        const size_t gb = (size_t)(c0 + t) * 1024 + kh * 128;
#pragma unroll
        for (int i = 0; i < 4; ++i) {
            const int kc = kc0 + i;
            half8 kv = *(const half8*)(kch + gb + kc * 8);
            half8 qv = *(const half8*)(qch + gb + kc * 8);
            const int chl = t * 16 + (kc ^ (t & 15));
            *(half8*)&Ksh[chl * 8] = kv;
            *(half8*)&Qsh[chl * 8] = qv;
        }
    }
    if (tid < 64) {
        float g = lgd[(size_t)(c0 + tid) * 16 + h];
#pragma unroll
        for (int off = 1; off < 64; off <<= 1) {
            float y = __shfl_up(g, off, 64);
            if (tid >= off) g += y;
        }
        Gs[tid] = g;
        Gam[tid] = expf(g);
        Bets[tid] = bet[(size_t)(c0 + tid) * 16 + h];
    }
    __syncthreads();

    _Float16* CHb = CH + (size_t)(c * 16 + h) * 36864;
    _Float16* Ug = CHb;
    _Float16* Wtg = CHb + 8192;
    _Float16* Khg = CHb + 16384;
    _Float16* Qgg = CHb + 24576;
    _Float16* Lg = CHb + 32768;

    {
        floatx4 accKK[4], accQK[4];
#pragma unroll
        for (int tt = 0; tt < 4; ++tt) { accKK[tt] = 0; accQK[tt] = 0; }
        half8 bfK[4];
#pragma unroll
        for (int ks = 0; ks < 4; ++ks) {
            const int i = wave * 16 + l15;
            const int kc = ks * 4 + quad;
            bfK[ks] = *(const half8*)&Ksh[(i * 16 + (kc ^ (i & 15))) * 8];
        }
#pragma unroll
        for (int tt = 0; tt < 4; ++tt) {
            const int t = tt * 16 + l15;
#pragma unroll
            for (int ks = 0; ks < 4; ++ks) {
                const int kc = ks * 4 + quad;
                const int chl = (t * 16 + (kc ^ (t & 15))) * 8;
                half8 afK = *(const half8*)&Ksh[chl];
                half8 afQ = *(const half8*)&Qsh[chl];
                accKK[tt] = __builtin_amdgcn_mfma_f32_16x16x32_f16(afK, bfK[ks], accKK[tt], 0, 0, 0);
                accQK[tt] = __builtin_amdgcn_mfma_f32_16x16x32_f16(afQ, bfK[ks], accQK[tt], 0, 0, 0);
            }
        }
        const int ii = wave * 16 + l15;
        const float Gi = Gs[ii];
#pragma unroll
        for (int tt = 0; tt < 4; ++tt)
#pragma unroll
            for (int r = 0; r < 4; ++r) {
                const int t = tt * 16 + quad * 4 + r;
                const float Gt = Gs[t];
                const float ratio = (ii <= t) ? expf(Gt - Gi) : 0.f;
                if (ii < t) Amat[t * 68 + ii] = Bets[t] * ratio * accKK[tt][r];
                Lg[t * 64 + ii] = (_Float16)((ii <= t) ? ratio * accQK[tt][r] : 0.f);
            }
    }
    __syncthreads();

    {
        const int j = tid;
        float x[64];
        if (j < 128) {
#pragma unroll
            for (int t = 0; t < 64; ++t)
                x[t] = Bets[t] * (float)vch[(size_t)(c0 + t) * 2048 + h * 128 + j];
        } else {
            const int k = j - 128;
#pragma unroll
            for (int t = 0; t < 64; ++t) {
                const int chl = t * 16 + ((k >> 3) ^ (t & 15));
                x[t] = Bets[t] * Gam[t] * (float)Ksh[chl * 8 + (k & 7)];
            }
        }
#pragma unroll
        for (int t = 1; t < 64; ++t) {
            const int nq = (t + 3) >> 2;
            float s0 = 0.f, s1 = 0.f, s2 = 0.f, s3 = 0.f;
#pragma unroll
            for (int q = 0; q < nq; ++q) {
                const float4 a = *(const float4*)&Amat[t * 68 + q * 4];
                s0 = fmaf(a.x, x[q * 4 + 0], s0);
                s1 = fmaf(a.y, x[q * 4 + 1], s1);
                s2 = fmaf(a.z, x[q * 4 + 2], s2);
                s3 = fmaf(a.w, x[q * 4 + 3], s3);
            }
            x[t] -= (s0 + s1) + (s2 + s3);
        }
        if (j < 128) {
#pragma unroll
            for (int t = 0; t < 64; t += 4) {
                half4 w4;
                w4[0] = (_Float16)x[t]; w4[1] = (_Float16)x[t + 1];
                w4[2] = (_Float16)x[t + 2]; w4[3] = (_Float16)x[t + 3];
                *(half4*)&Wtg[j * 64 + t] = w4;
            }
        } else {
            const int k = j - 128;
#pragma unroll
            for (int t = 0; t < 64; ++t) Ug[t * 128 + k] = (_Float16)x[t];
        }
    }

    {
        const float g63 = Gs[63];
        const int k = tid >> 1, cb = (tid & 1) * 32;
#pragma unroll
        for (int cc = 0; cc < 32; cc += 4) {
            half4 o4;
#pragma unroll
            for (int u = 0; u < 4; ++u) {
                const int ci = cb + cc + u;
                const int chl = ci * 16 + ((k >> 3) ^ (ci & 15));
                o4[u] = (_Float16)(expf(g63 - Gs[ci]) * (float)Ksh[chl * 8 + (k & 7)]);
            }
            *(half4*)&Khg[k * 64 + cb + cc] = o4;
        }
        const int cq = tid >> 2, kb = (tid & 3) * 4;
        const float gam = Gam[cq];
#pragma unroll
        for (int kc = 0; kc < 4; ++kc) {
            const int kcc = kb + kc;
            half8 q8 = *(const half8*)&Qsh[(cq * 16 + (kcc ^ (cq & 15))) * 8];
            half8 s8;
#pragma unroll
            for (int u = 0; u < 8; ++u) s8[u] = (_Float16)(gam * (float)q8[u]);
            *(half8*)&Qgg[cq * 128 + kcc * 8] = s8;
        }
        if (tid == 0) gamC[c * 16 + h] = Gam[63];
    }
}

// ---------------------------------------------------------------------------
// chunk_scan: 128 blocks (16 heads x 8 v-slices of 16), 256 threads.
// Waves split work; operands double-buffered global->VGPR; S^T/Dt in LDS.
// ---------------------------------------------------------------------------
struct ScanOps {
    half8 aU[4];
    half8 aQ[4];
    half8 aL[2];
    half8 aK[2][2];
    half4 wv;
    float gC;
};

__global__ __launch_bounds__(256) void chunk_scan(const _Float16* __restrict__ CH,
                                                  const float* __restrict__ gamC,
                                                  float* __restrict__ o) {
    const int h = blockIdx.x & 15;
    const int vsl = blockIdx.x >> 4;
    const int tid = threadIdx.x, lane = tid & 63, wave = tid >> 6;
    const int l15 = lane & 15, quad = lane >> 4;
    const int tw = wave * 16;
    const int kw = wave * 32;
    const int sKey = l15 << 1;
    const int dKey = (l15 << 1) & 14;

    __shared__ __align__(16) _Float16 Ssh[16 * 128];
    __shared__ __align__(16) _Float16 Dsh[16 * 64];

    *(half8*)&Ssh[tid * 8] = half8{0, 0, 0, 0, 0, 0, 0, 0};
    floatx4 Sacc[2];
    Sacc[0] = 0; Sacc[1] = 0;
    __syncthreads();

    auto loadOps = [&](ScanOps& S, int c) {
        const _Float16* CHb = CH + (size_t)(c * 16 + h) * 36864;
#pragma unroll
        for (int ks = 0; ks < 4; ++ks) {
            S.aU[ks] = *(const half8*)(CHb + (tw + l15) * 128 + ks * 32 + quad * 8);
            S.aQ[ks] = *(const half8*)(CHb + 24576 + (tw + l15) * 128 + ks * 32 + quad * 8);
        }
#pragma unroll
        for (int cs = 0; cs < 2; ++cs) {
            S.aL[cs] = *(const half8*)(CHb + 32768 + (tw + l15) * 64 + cs * 32 + quad * 8);
#pragma unroll
            for (int kt = 0; kt < 2; ++kt)
                S.aK[kt][cs] = *(const half8*)(CHb + 16384 + (kw + kt * 16 + l15) * 64 + cs * 32 + quad * 8);
        }
        S.wv = *(const half4*)(CHb + 8192 + (vsl * 16 + l15) * 64 + tw + quad * 4);
        S.gC = gamC[c * 16 + h];
    };

    auto chunkBody = [&](const ScanOps& S, int c) {
        half8 bs[4];
#pragma unroll
        for (int ks = 0; ks < 4; ++ks)
            bs[ks] = *(const half8*)&Ssh[(l15 * 32 + ((ks * 8 + quad * 2) ^ sKey)) * 4];
        floatx4 xa = {0.f, 0.f, 0.f, 0.f};
#pragma unroll
        for (int ks = 0; ks < 4; ++ks)
            xa = __builtin_amdgcn_mfma_f32_16x16x32_f16(S.aU[ks], bs[ks], xa, 0, 0, 0);
        half4 d4;
#pragma unroll
        for (int r = 0; r < 4; ++r) d4[r] = (_Float16)((float)S.wv[r] - xa[r]);
        *(half4*)&Dsh[(l15 * 16 + ((wave * 4 + quad) ^ dKey)) * 4] = d4;
        __syncthreads();

        half8 bd[2];
#pragma unroll
        for (int cs = 0; cs < 2; ++cs)
            bd[cs] = *(const half8*)&Dsh[(l15 * 16 + ((cs * 8 + quad * 2) ^ dKey)) * 4];
        floatx4 oacc = {0.f, 0.f, 0.f, 0.f};
#pragma unroll
        for (int ks = 0; ks < 4; ++ks)
            oacc = __builtin_amdgcn_mfma_f32_16x16x32_f16(S.aQ[ks], bs[ks], oacc, 0, 0, 0);
#pragma unroll
        for (int cs = 0; cs < 2; ++cs)
            oacc = __builtin_amdgcn_mfma_f32_16x16x32_f16(S.aL[cs], bd[cs], oacc, 0, 0, 0);
#pragma unroll
        for (int kt = 0; kt < 2; ++kt) {
#pragma unroll
            for (int r = 0; r < 4; ++r) Sacc[kt][r] *= S.gC;
#pragma unroll
            for (int cs = 0; cs < 2; ++cs)
                Sacc[kt] = __builtin_amdgcn_mfma_f32_16x16x32_f16(S.aK[kt][cs], bd[cs], Sacc[kt], 0, 0, 0);
        }
        const int col = h * 128 + vsl * 16 + l15;
#pragma unroll
        for (int r = 0; r < 4; ++r)
            o[(size_t)(c * 64 + tw + quad * 4 + r) * 2048 + col] = oacc[r];
#pragma unroll
        for (int kt = 0; kt < 2; ++kt) {
            half4 s4;
#pragma unroll
            for (int r = 0; r < 4; ++r) s4[r] = (_Float16)Sacc[kt][r];
            *(half4*)&Ssh[(l15 * 32 + ((wave * 8 + kt * 4 + quad) ^ sKey)) * 4] = s4;
        }
        __syncthreads();
    };

    ScanOps A_, B_;
    loadOps(A_, 0);
#pragma unroll 1
    for (int cc = 0; cc < 16; cc += 2) {
        loadOps(B_, cc + 1);
        chunkBody(A_, cc);
        if (cc + 2 < 16) loadOps(A_, cc + 2);
        chunkBody(B_, cc + 1);
    }
}

// ---------------------------------------------------------------------------
// Gated RMSNorm: xf = o * silu(z); xn = xf * rsqrt(mean(xf^2)+eps) * w
// ---------------------------------------------------------------------------
__global__ __launch_bounds__(64) void gated_norm(const float* __restrict__ o,
                                                 const _Float16* __restrict__ qkvz,
                                                 const float* __restrict__ nw,
                                                 _Float16* __restrict__ xn) {
    const int b = blockIdx.x;
    const int t = b >> 4;
    const int vh = b & 15;
    const int kh = vh >> 1;
    const int r = vh & 1;
    const float* op = o + (size_t)t * 2048 + vh * 128;
    const _Float16* zp = qkvz + (size_t)t * QKVZ_N + kh * 768 + 512 + r * 128;
    const int j = threadIdx.x * 2;
    const float2 ov = *(const float2*)(op + j);
    const half2t zv = *(const half2t*)(zp + j);
    const float z0 = (float)zv[0], z1 = (float)zv[1];
    const float f0 = ov.x * z0 / (1.f + expf(-z0));
    const float f1 = ov.y * z1 / (1.f + expf(-z1));
    float ss = f0 * f0 + f1 * f1;
#pragma unroll
    for (int m = 1; m < 64; m <<= 1) ss += __shfl_xor(ss, m, 64);
    const float rs = rsqrtf(ss * (1.f / 128.f) + 1e-6f);
    _Float16* xp = xn + (size_t)t * 2048 + vh * 128;
    half2t y;
    y[0] = (_Float16)(f0 * rs * nw[j]);
    y[1] = (_Float16)(f1 * rs * nw[j + 1]);
    *(half2t*)(xp + j) = y;
}

// ---------------------------------------------------------------------------
extern "C" void kernel_launch(void* const* d_in, const int* in_sizes, int n_in,
                              void* d_out, int out_size, void* d_ws, size_t ws_size,
                              hipStream_t stream) {
    const float* hidden  = (const float*)d_in[0];
    const float* w_qkvz  = (const float*)d_in[1];
    const float* w_ba    = (const float*)d_in[2];
    const float* conv_w  = (const float*)d_in[3];
    const float* dt_bias = (const float*)d_in[4];
    const float* A_log   = (const float*)d_in[5];
    const float* norm_w  = (const float*)d_in[6];
    const float* w_out   = (const float*)d_in[7];
    float* out = (float*)d_out;

    // workspace layout (~63.2 MB), lifetime-based overlaps:
    //   hidden_h overlaps o        (hidden_h dead after qkvz GEMM)
    //   CH + xn_h overlap wqkvz_h  (wqkvz_h dead after qkvz GEMM)
    char* w = (char*)d_ws;
    _Float16*  qkvz_h = (_Float16*)(w);                 // 12,582,912 B (fp16)
    _Float16*  qch    = (_Float16*)(w + 12713984);      //  2,097,152 B
    _Float16*  kch    = (_Float16*)(w + 14811136);      //  2,097,152 B
    _Float16*  vch    = (_Float16*)(w + 16908288);      //  4,194,304 B
    float*     lgd    = (float*)(w + 21102592);         //     65,536 B
    float*     bet    = (float*)(w + 21168128);         //     65,536 B
    float*     gamC   = (float*)(w + 21233664);         //      4,096 B
    float*     o      = (float*)(w + 21237760);         //  8,388,608 B
    _Float16*  hid_h  = (_Float16*)(w + 21237760);      //  overlaps o
    _Float16*  wqk_h  = (_Float16*)(w + 29626368);      // 25,165,824 B
    _Float16*  CH     = (_Float16*)(w + 29626368);      //  overlaps wqk_h
    _Float16*  xn_h   = (_Float16*)(w + 29626368 + 18874368);  // after CH
    _Float16*  wout_h = (_Float16*)(w + 54792192);      //  8,388,608 B

    const int n0 = HIDDEN * T_LEN / 4;       //  524,288 float4s
    const int n1 = QKVZ_N * HIDDEN / 4;      // 3,145,728
    const int n2 = VAL_DIM * HIDDEN / 4;     // 1,048,576
    cvt3<<<(n0 + n1 + n2 + 255) / 256, 256, 0, stream>>>(hidden, hid_h, n0,
                                                         w_qkvz, wqk_h, n1,
                                                         w_out, wout_h, n2);

    gemm_h16<4, _Float16><<<16 * 48, 256, 0, stream>>>(hid_h, wqk_h, qkvz_h, 16, 48, HIDDEN);
    gemm_ba_gates<<<T_LEN, 256, 0, stream>>>(hidden, w_ba, dt_bias, A_log, lgd, bet);
    conv_silu_l2<<<T_LEN, 512, 0, stream>>>(qkvz_h, conv_w, qch, kch, vch);
    chunk_prep<<<256, 256, 0, stream>>>(qch, kch, vch, lgd, bet, CH, gamC);
    chunk_scan<<<128, 256, 0, stream>>>(CH, gamC, o);
    gated_norm<<<T_LEN * 16, 64, 0, stream>>>(o, qkvz_h, norm_w, xn_h);
    gemm_h16<2, float><<<16 * 32, 256, 0, stream>>>(xn_h, wout_h, out, 16, 32, HIDDEN);
}